// Round 1
// baseline (705.933 us; speedup 1.0000x reference)
//
#include <hip/hip_runtime.h>
#include <math.h>

// Problem: B=4, NQ=8192, NKV=8192, D=256, H=8, HD=32, KP=256. ROWS = B*NQ = 32768.
// Rewrite: G = E^T x2, Hh = F^T x2  (only kernels touching NKV)
//          klow = G @ Wk, vlow = Hh @ Wv            [256x256 each]
//          per query row r: q = x1_r @ Wq; per head: s = q_h . klow_h^T * scale;
//          softmax; o_h = s @ vlow_h; y = o @ Wo.

// ---------------------------------------------------------------------------
// K1: partial G/Hh = E^T x2 (F^T x2). grid (16 tiles, 8 n-chunks, 2), 256 thr.
// part layout: [which][chunk][256][256]
__global__ __launch_bounds__(256) void k_etx2_partial(
    const float* __restrict__ x2, const float* __restrict__ E,
    const float* __restrict__ F, float* __restrict__ part) {
  __shared__ float e_s[16][68];
  __shared__ float x_s[16][68];
  const int t = threadIdx.x;
  const int tileK = (blockIdx.x & 3) * 64;   // KP dim
  const int tileD = (blockIdx.x >> 2) * 64;  // D dim
  const int chunk = blockIdx.y;
  const int which = blockIdx.z;
  const float* __restrict__ M = which ? F : E;
  float acc[4][4] = {};
  const int rb = (t >> 4) * 4;
  const int cb = (t & 15) * 4;
  const int lr = t >> 4;        // staging row 0..15
  const int lc = (t & 15) * 4;  // staging col 0..60
  const int nEnd = chunk * 1024 + 1024;
  for (int n0 = chunk * 1024; n0 < nEnd; n0 += 16) {
    float4 ev = *(const float4*)&M[(size_t)(n0 + lr) * 256 + tileK + lc];
    float4 xv = *(const float4*)&x2[(size_t)(n0 + lr) * 256 + tileD + lc];
    *(float4*)&e_s[lr][lc] = ev;
    *(float4*)&x_s[lr][lc] = xv;
    __syncthreads();
#pragma unroll
    for (int kk = 0; kk < 16; ++kk) {
      float a[4], b[4];
#pragma unroll
      for (int i = 0; i < 4; ++i) a[i] = e_s[kk][rb + i];
#pragma unroll
      for (int j = 0; j < 4; ++j) b[j] = x_s[kk][cb + j];
#pragma unroll
      for (int i = 0; i < 4; ++i)
#pragma unroll
        for (int j = 0; j < 4; ++j) acc[i][j] += a[i] * b[j];
    }
    __syncthreads();
  }
  float* __restrict__ p = part + ((size_t)which * 8 + chunk) * 65536;
#pragma unroll
  for (int i = 0; i < 4; ++i)
#pragma unroll
    for (int j = 0; j < 4; ++j)
      p[(tileK + rb + i) * 256 + (tileD + cb + j)] = acc[i][j];
}

// K1b: reduce the 8 n-chunk partials. gh = [G(65536) | Hh(65536)]. grid 512.
__global__ __launch_bounds__(256) void k_reduce_part(
    const float* __restrict__ part, float* __restrict__ gh) {
  const int oid = blockIdx.x * 256 + threadIdx.x;  // 0..131071
  const int which = oid >> 16;
  const int base = oid & 65535;
  const float* __restrict__ p = part + (size_t)which * 8 * 65536 + base;
  float s = 0.f;
#pragma unroll
  for (int c = 0; c < 8; ++c) s += p[c * 65536];
  gh[oid] = s;
}

// K2: klow = G @ Wk, vlow = Hh @ Wv. grid (16, 2), 256 thr, 64x64 tiles.
__global__ __launch_bounds__(256) void k_lowproj(
    const float* __restrict__ gh, const float* __restrict__ Wk,
    const float* __restrict__ Wv, float* __restrict__ kvlow) {
  __shared__ float a_s[64][17];
  __shared__ float b_s[16][68];
  const int t = threadIdx.x;
  const int which = blockIdx.y;
  const float* __restrict__ A = gh + (size_t)which * 65536;
  const float* __restrict__ W = which ? Wv : Wk;
  float* __restrict__ outp = kvlow + (size_t)which * 65536;
  const int rt = (blockIdx.x >> 2) * 64;
  const int ct = (blockIdx.x & 3) * 64;
  float acc[4][4] = {};
  const int rb = (t >> 4) * 4;
  const int cb = (t & 15) * 4;
  for (int k0 = 0; k0 < 256; k0 += 16) {
    const int ar = t >> 2, ac = (t & 3) * 4;
    float4 av = *(const float4*)&A[(size_t)(rt + ar) * 256 + k0 + ac];
    a_s[ar][ac] = av.x; a_s[ar][ac + 1] = av.y;
    a_s[ar][ac + 2] = av.z; a_s[ar][ac + 3] = av.w;
    const int br = t >> 4, bc = (t & 15) * 4;
    *(float4*)&b_s[br][bc] = *(const float4*)&W[(size_t)(k0 + br) * 256 + ct + bc];
    __syncthreads();
#pragma unroll
    for (int kk = 0; kk < 16; ++kk) {
      float a[4], b[4];
#pragma unroll
      for (int i = 0; i < 4; ++i) a[i] = a_s[rb + i][kk];
#pragma unroll
      for (int j = 0; j < 4; ++j) b[j] = b_s[kk][cb + j];
#pragma unroll
      for (int i = 0; i < 4; ++i)
#pragma unroll
        for (int j = 0; j < 4; ++j) acc[i][j] += a[i] * b[j];
    }
    __syncthreads();
  }
#pragma unroll
  for (int i = 0; i < 4; ++i)
#pragma unroll
    for (int j = 0; j < 4; ++j)
      outp[(size_t)(rt + rb + i) * 256 + ct + cb + j] = acc[i][j];
}

// K3: fused q-proj + attention + out-proj. grid 1024 (32 rows/block), 256 thr.
__global__ __launch_bounds__(256) void k_fused(
    const float* __restrict__ x1, const float* __restrict__ Wq,
    const float* __restrict__ Wo, const float* __restrict__ klow,
    const float* __restrict__ vlow, float* __restrict__ out) {
  __shared__ float q_s[32][264];  // q rows (padded)
  __shared__ float s_s[32][264];  // scores; reused as W-tile staging
  __shared__ float o_s[32][264];  // attention output
  __shared__ float kv_s[8192];    // swizzled K/V head slice [256][32]
  __shared__ float x_s[32][33];
  const int t = threadIdx.x;
  const size_t r0 = (size_t)blockIdx.x * 32;

  // ---- phase 1: q_s = x1[r0:r0+32] @ Wq
  {
    const int rb = (t >> 5) * 4;
    const int cb = (t & 31) * 8;
    float acc[4][8] = {};
    for (int kt = 0; kt < 256; kt += 32) {
      {  // stage x tile 32x32
        const int lr = t >> 3, lc = (t & 7) * 4;
        float4 v = *(const float4*)&x1[(r0 + lr) * 256 + kt + lc];
        x_s[lr][lc] = v.x; x_s[lr][lc + 1] = v.y;
        x_s[lr][lc + 2] = v.z; x_s[lr][lc + 3] = v.w;
      }
      {  // stage Wq tile 32x256 into s_s
        const int lr = t >> 3, lcb = (t & 7) * 32;
        const float* wp = &Wq[(size_t)(kt + lr) * 256 + lcb];
#pragma unroll
        for (int c = 0; c < 32; c += 4)
          *(float4*)&s_s[lr][lcb + c] = *(const float4*)&wp[c];
      }
      __syncthreads();
#pragma unroll
      for (int kk = 0; kk < 32; ++kk) {
        float a[4], w[8];
#pragma unroll
        for (int i = 0; i < 4; ++i) a[i] = x_s[rb + i][kk];
        *(float4*)&w[0] = *(const float4*)&s_s[kk][cb];
        *(float4*)&w[4] = *(const float4*)&s_s[kk][cb + 4];
#pragma unroll
        for (int i = 0; i < 4; ++i)
#pragma unroll
          for (int j = 0; j < 8; ++j) acc[i][j] += a[i] * w[j];
      }
      __syncthreads();
    }
#pragma unroll
    for (int i = 0; i < 4; ++i)
#pragma unroll
      for (int j = 0; j < 8; ++j) q_s[rb + i][cb + j] = acc[i][j];
  }
  __syncthreads();

  // ---- phase 2: per-head scores -> softmax -> PV
  const float scale = 0.17677669529663687f;  // 1/sqrt(32)
  for (int h = 0; h < 8; ++h) {
    __syncthreads();  // prev head's PV done before restaging kv_s / s_s
    {  // stage K head slice, rotation swizzle: [k][(j+k)&31]
#pragma unroll
      for (int i = 0; i < 32; ++i) {
        const int idx = t + 256 * i;
        const int k = idx >> 5, j = idx & 31;
        kv_s[k * 32 + ((j + k) & 31)] = klow[(size_t)k * 256 + h * 32 + j];
      }
    }
    __syncthreads();
    {  // scores: s[r][k] = scale * sum_j q[r][h*32+j]*K[k][j]
      const int rb2 = (t >> 5) * 4;
      const int kbase = t & 31;
      float acc[4][8] = {};
#pragma unroll 4
      for (int j = 0; j < 32; ++j) {
        float qv[4];
#pragma unroll
        for (int i = 0; i < 4; ++i) qv[i] = q_s[rb2 + i][h * 32 + j];
#pragma unroll
        for (int m = 0; m < 8; ++m) {
          const int k = kbase + 32 * m;
          const float kvv = kv_s[k * 32 + ((j + k) & 31)];
#pragma unroll
          for (int i = 0; i < 4; ++i) acc[i][m] += qv[i] * kvv;
        }
      }
#pragma unroll
      for (int i = 0; i < 4; ++i)
#pragma unroll
        for (int m = 0; m < 8; ++m)
          s_s[rb2 + i][kbase + 32 * m] = acc[i][m] * scale;
    }
    __syncthreads();
    {  // softmax per row (8 threads/row)
      const int r = t >> 3, ls = t & 7;
      float mx = -1e30f;
#pragma unroll
      for (int i = 0; i < 32; ++i) mx = fmaxf(mx, s_s[r][ls + 8 * i]);
      mx = fmaxf(mx, __shfl_xor(mx, 1));
      mx = fmaxf(mx, __shfl_xor(mx, 2));
      mx = fmaxf(mx, __shfl_xor(mx, 4));
      float sum = 0.f;
#pragma unroll
      for (int i = 0; i < 32; ++i) {
        const float e = __expf(s_s[r][ls + 8 * i] - mx);
        s_s[r][ls + 8 * i] = e;
        sum += e;
      }
      sum += __shfl_xor(sum, 1);
      sum += __shfl_xor(sum, 2);
      sum += __shfl_xor(sum, 4);
      const float rinv = 1.0f / sum;
#pragma unroll
      for (int i = 0; i < 32; ++i) s_s[r][ls + 8 * i] *= rinv;
    }
    {  // stage V head slice, 4-aligned rotation: [k][(j+4*(k&7))&31]
#pragma unroll
      for (int i = 0; i < 32; ++i) {
        const int idx = t + 256 * i;
        const int k = idx >> 5, j = idx & 31;
        kv_s[k * 32 + ((j + ((k & 7) << 2)) & 31)] =
            vlow[(size_t)k * 256 + h * 32 + j];
      }
    }
    __syncthreads();
    {  // PV: o[r][h*32+jb..+4] = sum_k attn[r][k] * V[k][jb..]
      const int r = t >> 3, jb = (t & 7) * 4;
      float acc[4] = {};
      for (int k = 0; k < 256; ++k) {
        const float a = s_s[r][k];
        const int rot = (k & 7) << 2;
        float4 v = *(const float4*)&kv_s[k * 32 + ((jb + rot) & 31)];
        acc[0] += a * v.x; acc[1] += a * v.y;
        acc[2] += a * v.z; acc[3] += a * v.w;
      }
#pragma unroll
      for (int i = 0; i < 4; ++i) o_s[r][h * 32 + jb + i] = acc[i];
    }
  }
  __syncthreads();

  // ---- phase 3: out = o_s @ Wo
  {
    const int rb = (t >> 5) * 4;
    const int cb = (t & 31) * 8;
    float acc[4][8] = {};
    for (int kt = 0; kt < 256; kt += 32) {
      {  // stage Wo tile into s_s
        const int lr = t >> 3, lcb = (t & 7) * 32;
        const float* wp = &Wo[(size_t)(kt + lr) * 256 + lcb];
#pragma unroll
        for (int c = 0; c < 32; c += 4)
          *(float4*)&s_s[lr][lcb + c] = *(const float4*)&wp[c];
      }
      __syncthreads();
#pragma unroll
      for (int kk = 0; kk < 32; ++kk) {
        float a[4], w[8];
#pragma unroll
        for (int i = 0; i < 4; ++i) a[i] = o_s[rb + i][kt + kk];
        *(float4*)&w[0] = *(const float4*)&s_s[kk][cb];
        *(float4*)&w[4] = *(const float4*)&s_s[kk][cb + 4];
#pragma unroll
        for (int i = 0; i < 4; ++i)
#pragma unroll
          for (int j = 0; j < 8; ++j) acc[i][j] += a[i] * w[j];
      }
      __syncthreads();
    }
#pragma unroll
    for (int i = 0; i < 4; ++i) {
      float4 v0 = make_float4(acc[i][0], acc[i][1], acc[i][2], acc[i][3]);
      float4 v1 = make_float4(acc[i][4], acc[i][5], acc[i][6], acc[i][7]);
      *(float4*)&out[(r0 + rb + i) * 256 + cb] = v0;
      *(float4*)&out[(r0 + rb + i) * 256 + cb + 4] = v1;
    }
  }
}

extern "C" void kernel_launch(void* const* d_in, const int* in_sizes, int n_in,
                              void* d_out, int out_size, void* d_ws, size_t ws_size,
                              hipStream_t stream) {
  const float* x1 = (const float*)d_in[0];
  const float* x2 = (const float*)d_in[1];
  const float* Wq = (const float*)d_in[2];
  const float* Wk = (const float*)d_in[3];
  const float* Wv = (const float*)d_in[4];
  const float* Wo = (const float*)d_in[5];
  const float* E  = (const float*)d_in[6];
  const float* F  = (const float*)d_in[7];
  float* out = (float*)d_out;
  float* ws = (float*)d_ws;
  // ws layout (floats): part [2][8][65536] @0 ; G|Hh @1048576 ; klow|vlow @1179648
  float* part  = ws;
  float* gh    = ws + 1048576;
  float* kvlow = ws + 1179648;

  k_etx2_partial<<<dim3(16, 8, 2), 256, 0, stream>>>(x2, E, F, part);
  k_reduce_part<<<512, 256, 0, stream>>>(part, gh);
  k_lowproj<<<dim3(16, 2), 256, 0, stream>>>(gh, Wk, Wv, kvlow);
  k_fused<<<1024, 256, 0, stream>>>(x1, Wq, Wo, kvlow, kvlow + 65536, out);
}

// Round 2
// 148.846 us; speedup vs baseline: 4.7427x; 4.7427x over previous
//
#include <hip/hip_runtime.h>
#include <math.h>
#include <stdint.h>

// B=4, NQ=8192, NKV=8192, D=256, H=8, HD=32, KP=256. ROWS = 32768.
// G = E^T x2, Hh = F^T x2 ; klow = G@Wk, vlow = Hh@Wv (f32 path, unchanged)
// prep: Wqt=bf16(Wq^T * scale*log2e), Wot=bf16(Wo^T), klowb=bf16(klow),
//       vtb = bf16(vlow^T per head), XOR-swizzled for conflict-free ds_read.
// fused: per 64 query rows: Q=x1@Wq (MFMA) -> per head: St=mfma(klow,Q),
//        register softmax(2^x), PV via wave-private P repack, Y += Oh@Wot_h.

typedef unsigned short ushort_t;
typedef __attribute__((ext_vector_type(8))) short bf16x8;
typedef __attribute__((ext_vector_type(4))) float f32x4;

__device__ __forceinline__ f32x4 MFMA(bf16x8 a, bf16x8 b, f32x4 c) {
  return __builtin_amdgcn_mfma_f32_16x16x32_bf16(a, b, c, 0, 0, 0);
}
__device__ __forceinline__ ushort_t f2bf(float x) {
  uint32_t u = __float_as_uint(x);
  u += 0x7fffu + ((u >> 16) & 1u);
  return (ushort_t)(u >> 16);
}
#define GLDS(gsrc, ldst)                                                    \
  __builtin_amdgcn_global_load_lds(                                         \
      (const __attribute__((address_space(1))) uint32_t*)(const void*)(gsrc), \
      (__attribute__((address_space(3))) uint32_t*)(void*)(ldst), 16, 0, 0)

// ---------------------------------------------------------------------------
// K1: partial G/Hh = E^T x2 (F^T x2). grid (16, 8, 2), 256 thr. (unchanged)
__global__ __launch_bounds__(256) void k_etx2_partial(
    const float* __restrict__ x2, const float* __restrict__ E,
    const float* __restrict__ F, float* __restrict__ part) {
  __shared__ float e_s[16][68];
  __shared__ float x_s[16][68];
  const int t = threadIdx.x;
  const int tileK = (blockIdx.x & 3) * 64;
  const int tileD = (blockIdx.x >> 2) * 64;
  const int chunk = blockIdx.y;
  const int which = blockIdx.z;
  const float* __restrict__ M = which ? F : E;
  float acc[4][4] = {};
  const int rb = (t >> 4) * 4;
  const int cb = (t & 15) * 4;
  const int lr = t >> 4;
  const int lc = (t & 15) * 4;
  const int nEnd = chunk * 1024 + 1024;
  for (int n0 = chunk * 1024; n0 < nEnd; n0 += 16) {
    float4 ev = *(const float4*)&M[(size_t)(n0 + lr) * 256 + tileK + lc];
    float4 xv = *(const float4*)&x2[(size_t)(n0 + lr) * 256 + tileD + lc];
    *(float4*)&e_s[lr][lc] = ev;
    *(float4*)&x_s[lr][lc] = xv;
    __syncthreads();
#pragma unroll
    for (int kk = 0; kk < 16; ++kk) {
      float a[4], b[4];
#pragma unroll
      for (int i = 0; i < 4; ++i) a[i] = e_s[kk][rb + i];
#pragma unroll
      for (int j = 0; j < 4; ++j) b[j] = x_s[kk][cb + j];
#pragma unroll
      for (int i = 0; i < 4; ++i)
#pragma unroll
        for (int j = 0; j < 4; ++j) acc[i][j] += a[i] * b[j];
    }
    __syncthreads();
  }
  float* __restrict__ p = part + ((size_t)which * 8 + chunk) * 65536;
#pragma unroll
  for (int i = 0; i < 4; ++i)
#pragma unroll
    for (int j = 0; j < 4; ++j)
      p[(tileK + rb + i) * 256 + (tileD + cb + j)] = acc[i][j];
}

// K1b: reduce 8 partials. (unchanged)
__global__ __launch_bounds__(256) void k_reduce_part(
    const float* __restrict__ part, float* __restrict__ gh) {
  const int oid = blockIdx.x * 256 + threadIdx.x;
  const int which = oid >> 16;
  const int base = oid & 65535;
  const float* __restrict__ p = part + (size_t)which * 8 * 65536 + base;
  float s = 0.f;
#pragma unroll
  for (int c = 0; c < 8; ++c) s += p[c * 65536];
  gh[oid] = s;
}

// K2: klow = G @ Wk, vlow = Hh @ Wv. (unchanged)
__global__ __launch_bounds__(256) void k_lowproj(
    const float* __restrict__ gh, const float* __restrict__ Wk,
    const float* __restrict__ Wv, float* __restrict__ kvlow) {
  __shared__ float a_s[64][17];
  __shared__ float b_s[16][68];
  const int t = threadIdx.x;
  const int which = blockIdx.y;
  const float* __restrict__ A = gh + (size_t)which * 65536;
  const float* __restrict__ W = which ? Wv : Wk;
  float* __restrict__ outp = kvlow + (size_t)which * 65536;
  const int rt = (blockIdx.x >> 2) * 64;
  const int ct = (blockIdx.x & 3) * 64;
  float acc[4][4] = {};
  const int rb = (t >> 4) * 4;
  const int cb = (t & 15) * 4;
  for (int k0 = 0; k0 < 256; k0 += 16) {
    const int ar = t >> 2, ac = (t & 3) * 4;
    float4 av = *(const float4*)&A[(size_t)(rt + ar) * 256 + k0 + ac];
    a_s[ar][ac] = av.x; a_s[ar][ac + 1] = av.y;
    a_s[ar][ac + 2] = av.z; a_s[ar][ac + 3] = av.w;
    const int br = t >> 4, bc = (t & 15) * 4;
    *(float4*)&b_s[br][bc] = *(const float4*)&W[(size_t)(k0 + br) * 256 + ct + bc];
    __syncthreads();
#pragma unroll
    for (int kk = 0; kk < 16; ++kk) {
      float a[4], b[4];
#pragma unroll
      for (int i = 0; i < 4; ++i) a[i] = a_s[rb + i][kk];
#pragma unroll
      for (int j = 0; j < 4; ++j) b[j] = b_s[kk][cb + j];
#pragma unroll
      for (int i = 0; i < 4; ++i)
#pragma unroll
        for (int j = 0; j < 4; ++j) acc[i][j] += a[i] * b[j];
    }
    __syncthreads();
  }
#pragma unroll
  for (int i = 0; i < 4; ++i)
#pragma unroll
    for (int j = 0; j < 4; ++j)
      outp[(size_t)(rt + rb + i) * 256 + ct + cb + j] = acc[i][j];
}

// K3-prep: bf16 conversions/transposes. grid (256, 4), 256 thr.
// scale' = 1/sqrt(32) * log2(e) folded into Wq (exp2-domain softmax).
__global__ __launch_bounds__(256) void k_prep(
    const float* __restrict__ Wq, const float* __restrict__ Wo,
    const float* __restrict__ kvlow, ushort_t* __restrict__ wqt,
    ushort_t* __restrict__ wot, ushort_t* __restrict__ klowb,
    ushort_t* __restrict__ vtb) {
  const int id = blockIdx.x * 256 + threadIdx.x;  // 0..65535
  const int task = blockIdx.y;
  if (task == 0) {
    int n = id >> 8, k = id & 255;
    wqt[id] = f2bf(Wq[k * 256 + n] * 0.25503488f);
  } else if (task == 1) {
    int n = id >> 8, k = id & 255;
    wot[id] = f2bf(Wo[k * 256 + n]);
  } else if (task == 2) {
    klowb[id] = f2bf(kvlow[id]);
  } else {
    // vtb[h][kh][d][kl ^ ((d&7)<<3)] = bf16(vlow[kh*128+kl][h*32+d])
    int kl = id & 127;
    int d = (id >> 7) & 31;
    int kh = (id >> 12) & 1;
    int h = id >> 13;
    int ksw = kl ^ ((d & 7) << 3);
    vtb[(((h * 2 + kh) * 32 + d) << 7) + ksw] =
        f2bf(kvlow[65536 + (kh * 128 + kl) * 256 + h * 32 + d]);
  }
}

// K4: fused MFMA kernel. grid 512, 256 thr (4 waves x 16 rows). LDS 58 KB.
__global__ __launch_bounds__(256, 2) void k_fused_mfma(
    const float* __restrict__ x1, const ushort_t* __restrict__ wqt,
    const ushort_t* __restrict__ wot, const ushort_t* __restrict__ klowb,
    const ushort_t* __restrict__ vtb, float* __restrict__ out) {
  __shared__ __align__(16) ushort_t q_lds[16384];     // [64 rows][512B], XOR-swz
  __shared__ __align__(16) ushort_t wstage[2][4096];  // 2 x 8KB chunk dbuf
  __shared__ __align__(16) ushort_t o_slice[4][640];  // per-wave [16][40]
  __shared__ __align__(16) uint32_t p_buf[4][320];    // per-wave [16][20]
  const int t = threadIdx.x;
  const int wv = t >> 6, ln = t & 63;
  const int l15 = ln & 15, g = ln >> 4;
  const size_t r0 = (size_t)blockIdx.x * 64;
  char* qb = (char*)q_lds;

  // chunk staging: 8KB = 512 x 16B units; unit u = rnd*256 + wv*64 + lane.
  auto stage_w = [&](const ushort_t* base, int row0, int wbyte, int buf) {
    // [128 rows][64B window] of a [256][256] bf16 matrix (512B rows)
#pragma unroll
    for (int rnd = 0; rnd < 2; ++rnd) {
      int u = rnd * 256 + wv * 64 + ln;
      const ushort_t* gsrc =
          base + (size_t)(row0 + (u >> 2)) * 256 + (wbyte >> 1) + (u & 3) * 8;
      GLDS(gsrc, &wstage[buf][rnd * 2048 + wv * 512]);
    }
  };
  auto stage_c = [&](const ushort_t* base, int buf) {  // contiguous 8KB
#pragma unroll
    for (int rnd = 0; rnd < 2; ++rnd) {
      int u = rnd * 256 + wv * 64 + ln;
      GLDS(base + u * 8, &wstage[buf][rnd * 2048 + wv * 512]);
    }
  };

  // ---- phase 1: Q = x1 @ Wq^T (scaled), 16 chunks of Wqt --------------------
  f32x4 qacc[16];
#pragma unroll
  for (int i = 0; i < 16; ++i) qacc[i] = {0.f, 0.f, 0.f, 0.f};

  stage_w(wqt, 0, 0, 0);  // chunk 0
  const float* xrow = x1 + (r0 + wv * 16 + l15) * 256;
  float4 xa = *(const float4*)(xrow + g * 8);
  float4 xb = *(const float4*)(xrow + g * 8 + 4);
  __syncthreads();

  for (int ci = 0; ci < 16; ++ci) {
    const int nh = ci & 1;
    if (ci < 15)
      stage_w(wqt, ((ci + 1) & 1) * 128, ((ci + 1) >> 1) * 64, (ci + 1) & 1);
    else
      stage_w(klowb, 0, 0, 0);  // head 0, klow kh0
    bf16x8 afrag;
    afrag[0] = (short)f2bf(xa.x); afrag[1] = (short)f2bf(xa.y);
    afrag[2] = (short)f2bf(xa.z); afrag[3] = (short)f2bf(xa.w);
    afrag[4] = (short)f2bf(xb.x); afrag[5] = (short)f2bf(xb.y);
    afrag[6] = (short)f2bf(xb.z); afrag[7] = (short)f2bf(xb.w);
    const ushort_t* cw = wstage[ci & 1];
#pragma unroll
    for (int tt = 0; tt < 8; ++tt) {
      bf16x8 bfr = *(const bf16x8*)&cw[(tt * 16 + l15) * 32 + g * 8];
      qacc[nh * 8 + tt] = MFMA(afrag, bfr, qacc[nh * 8 + tt]);
    }
    if (nh == 1 && ci < 15) {  // prefetch next ks of x1
      int ks = (ci >> 1) + 1;
      xa = *(const float4*)(xrow + ks * 32 + g * 8);
      xb = *(const float4*)(xrow + ks * 32 + g * 8 + 4);
    }
    __syncthreads();
  }
  // write Q (bf16) to q_lds, XOR-swizzled rows. Wave-private rows.
#pragma unroll
  for (int tt = 0; tt < 16; ++tt)
#pragma unroll
    for (int r = 0; r < 4; ++r) {
      int row = wv * 16 + g * 4 + r;
      int lcol = (tt * 16 + l15) * 2;
      *(ushort_t*)(qb + row * 512 + (lcol ^ ((row & 7) << 4))) =
          f2bf(qacc[tt][r]);
    }
  __builtin_amdgcn_sched_barrier(0);

  // ---- phase 2: per head: scores -> softmax -> PV -> Y-partial --------------
  f32x4 yacc[16];
#pragma unroll
  for (int i = 0; i < 16; ++i) yacc[i] = {0.f, 0.f, 0.f, 0.f};

  for (int h = 0; h < 8; ++h) {
    // iter A: klow kh0 in buf0. St tiles 0..7.  (St = mfma(klow, Q))
    stage_w(klowb, 128, h * 64, 1);
    int qrow = wv * 16 + l15;
    bf16x8 qfrag = *(const bf16x8*)(qb + qrow * 512 +
                                    ((h * 64 + g * 16) ^ ((l15 & 7) << 4)));
    f32x4 s[16];
    {
      const ushort_t* ck = wstage[0];
#pragma unroll
      for (int tt = 0; tt < 8; ++tt) {
        bf16x8 afr = *(const bf16x8*)&ck[(tt * 16 + l15) * 32 + g * 8];
        f32x4 z = {0.f, 0.f, 0.f, 0.f};
        s[tt] = MFMA(afr, qfrag, z);
      }
    }
    __syncthreads();
    // iter B: klow kh1 in buf1. St tiles 8..15.
    stage_c(vtb + (h * 2 + 0) * 4096, 0);
    {
      const ushort_t* ck = wstage[1];
#pragma unroll
      for (int tt = 0; tt < 8; ++tt) {
        bf16x8 afr = *(const bf16x8*)&ck[(tt * 16 + l15) * 32 + g * 8];
        f32x4 z = {0.f, 0.f, 0.f, 0.f};
        s[8 + tt] = MFMA(afr, qfrag, z);
      }
    }
    __syncthreads();
    // iter C: vt kh0 in buf0. softmax (registers) + PV ks 0..3.
    stage_c(vtb + (h * 2 + 1) * 4096, 1);
    float m = -3.0e38f;
#pragma unroll
    for (int tt = 0; tt < 16; ++tt)
#pragma unroll
      for (int r = 0; r < 4; ++r) m = fmaxf(m, s[tt][r]);
    m = fmaxf(m, __shfl_xor(m, 16));
    m = fmaxf(m, __shfl_xor(m, 32));
    float sum = 0.f;
#pragma unroll
    for (int tt = 0; tt < 16; ++tt)
#pragma unroll
      for (int r = 0; r < 4; ++r) {
        float e = exp2f(s[tt][r] - m);  // log2e folded into Wq scale
        s[tt][r] = e;
        sum += e;
      }
    sum += __shfl_xor(sum, 16);
    sum += __shfl_xor(sum, 32);
    float rinv = 1.0f / sum;
    uint32_t pw[16][2];
#pragma unroll
    for (int tt = 0; tt < 16; ++tt)
#pragma unroll
      for (int p = 0; p < 2; ++p)
        pw[tt][p] = (uint32_t)f2bf(s[tt][2 * p] * rinv) |
                    ((uint32_t)f2bf(s[tt][2 * p + 1] * rinv) << 16);
    f32x4 oacc[2];
    oacc[0] = {0.f, 0.f, 0.f, 0.f};
    oacc[1] = {0.f, 0.f, 0.f, 0.f};
    uint32_t* pbw = &p_buf[wv][l15 * 20];
    {
      const char* cv = (const char*)wstage[0];
#pragma unroll
      for (int ksl = 0; ksl < 4; ++ksl) {
        pbw[2 * g + 0] = pw[2 * ksl][0];
        pbw[2 * g + 1] = pw[2 * ksl][1];
        pbw[8 + 2 * g + 0] = pw[2 * ksl + 1][0];
        pbw[8 + 2 * g + 1] = pw[2 * ksl + 1][1];
        __builtin_amdgcn_sched_barrier(0);
        bf16x8 pfr = *(const bf16x8*)&p_buf[wv][l15 * 20 + 4 * g];
#pragma unroll
        for (int nt = 0; nt < 2; ++nt) {
          bf16x8 vfr = *(const bf16x8*)(cv + (nt * 16 + l15) * 256 +
                                        ((ksl * 64 + g * 16) ^ ((l15 & 7) << 4)));
          oacc[nt] = MFMA(pfr, vfr, oacc[nt]);
        }
        __builtin_amdgcn_sched_barrier(0);
      }
    }
    __syncthreads();
    // iter D: vt kh1 in buf1. PV ks 4..7, then O_h -> o_slice.
    stage_w(wot, 0, h * 64, 0);
    {
      const char* cv = (const char*)wstage[1];
#pragma unroll
      for (int ksl = 0; ksl < 4; ++ksl) {
        pbw[2 * g + 0] = pw[8 + 2 * ksl][0];
        pbw[2 * g + 1] = pw[8 + 2 * ksl][1];
        pbw[8 + 2 * g + 0] = pw[9 + 2 * ksl][0];
        pbw[8 + 2 * g + 1] = pw[9 + 2 * ksl][1];
        __builtin_amdgcn_sched_barrier(0);
        bf16x8 pfr = *(const bf16x8*)&p_buf[wv][l15 * 20 + 4 * g];
#pragma unroll
        for (int nt = 0; nt < 2; ++nt) {
          bf16x8 vfr = *(const bf16x8*)(cv + (nt * 16 + l15) * 256 +
                                        ((ksl * 64 + g * 16) ^ ((l15 & 7) << 4)));
          oacc[nt] = MFMA(pfr, vfr, oacc[nt]);
        }
        __builtin_amdgcn_sched_barrier(0);
      }
    }
#pragma unroll
    for (int nt = 0; nt < 2; ++nt)
#pragma unroll
      for (int r = 0; r < 4; ++r)
        o_slice[wv][(g * 4 + r) * 40 + nt * 16 + l15] = f2bf(oacc[nt][r]);
    __builtin_amdgcn_sched_barrier(0);
    __syncthreads();
    // iter E: wot nh0 in buf0. Y tiles 0..7.
    stage_w(wot, 128, h * 64, 1);
    bf16x8 ofrag = *(const bf16x8*)&o_slice[wv][l15 * 40 + g * 8];
    {
      const ushort_t* cw = wstage[0];
#pragma unroll
      for (int tt = 0; tt < 8; ++tt) {
        bf16x8 bfr = *(const bf16x8*)&cw[(tt * 16 + l15) * 32 + g * 8];
        yacc[tt] = MFMA(ofrag, bfr, yacc[tt]);
      }
    }
    __syncthreads();
    // iter F: wot nh1 in buf1. Y tiles 8..15.
    if (h < 7) stage_w(klowb, 0, (h + 1) * 64, 0);
    {
      const ushort_t* cw = wstage[1];
#pragma unroll
      for (int tt = 0; tt < 8; ++tt) {
        bf16x8 bfr = *(const bf16x8*)&cw[(tt * 16 + l15) * 32 + g * 8];
        yacc[8 + tt] = MFMA(ofrag, bfr, yacc[8 + tt]);
      }
    }
    __syncthreads();
  }

  // ---- epilogue: store Y (f32) ---------------------------------------------
#pragma unroll
  for (int tt = 0; tt < 16; ++tt)
#pragma unroll
    for (int r = 0; r < 4; ++r)
      out[(r0 + wv * 16 + g * 4 + r) * 256 + tt * 16 + l15] = yacc[tt][r];
}

extern "C" void kernel_launch(void* const* d_in, const int* in_sizes, int n_in,
                              void* d_out, int out_size, void* d_ws, size_t ws_size,
                              hipStream_t stream) {
  const float* x1 = (const float*)d_in[0];
  const float* x2 = (const float*)d_in[1];
  const float* Wq = (const float*)d_in[2];
  const float* Wk = (const float*)d_in[3];
  const float* Wv = (const float*)d_in[4];
  const float* Wo = (const float*)d_in[5];
  const float* E  = (const float*)d_in[6];
  const float* F  = (const float*)d_in[7];
  float* out = (float*)d_out;
  float* ws = (float*)d_ws;
  // ws: part [2][8][65536] @0 ; G|Hh @1048576 ; klow|vlow @1179648 ;
  //     bf16 region @1310720 floats: wqt | wot | klowb | vtb (65536 each)
  float* part = ws;
  float* gh = ws + 1048576;
  float* kvlow = ws + 1179648;
  ushort_t* wqt = (ushort_t*)(ws + 1310720);
  ushort_t* wot = wqt + 65536;
  ushort_t* klowb = wot + 65536;
  ushort_t* vtb = klowb + 65536;

  k_etx2_partial<<<dim3(16, 8, 2), 256, 0, stream>>>(x2, E, F, part);
  k_reduce_part<<<512, 256, 0, stream>>>(part, gh);
  k_lowproj<<<dim3(16, 2), 256, 0, stream>>>(gh, Wk, Wv, kvlow);
  k_prep<<<dim3(256, 4), 256, 0, stream>>>(Wq, Wo, kvlow, wqt, wot, klowb, vtb);
  k_fused_mfma<<<512, 256, 0, stream>>>(x1, wqt, wot, klowb, vtb, out);
}

// Round 3
// 105.647 us; speedup vs baseline: 6.6820x; 1.4089x over previous
//
#include <hip/hip_runtime.h>
#include <math.h>
#include <stdint.h>

// B=4, NQ=8192, NKV=8192, D=256, H=8, HD=32, KP=256. ROWS = 32768.
// Pipeline:
//  k_transpose: x2,E,F [8192][256] f32 -> xt fp16 [3][256][8192] (transposed)
//  k_etx2_mfma: G = E^T x2, Hh = F^T x2 via fp16 MFMA split-K -> f32 partials
//  k_reduce_part: sum 16 K-chunk partials -> gh = [G|Hh]
//  k_lowproj: klow = G@Wk, vlow = Hh@Wv (f32)
//  k_prep: bf16 conversions (Wq^T*scale*log2e, Wo^T, klow, vlow^T swizzled)
//  k_fused_mfma: Q=x1@Wq -> per head St=mfma(klow,Q), reg softmax(2^x),
//                PV via wave-private repack, Y += Oh@Wot_h.

typedef unsigned short ushort_t;
typedef __attribute__((ext_vector_type(8))) short bf16x8;
typedef __attribute__((ext_vector_type(8))) _Float16 f16x8;
typedef __attribute__((ext_vector_type(4))) float f32x4;

__device__ __forceinline__ f32x4 MFMA(bf16x8 a, bf16x8 b, f32x4 c) {
  return __builtin_amdgcn_mfma_f32_16x16x32_bf16(a, b, c, 0, 0, 0);
}
__device__ __forceinline__ f32x4 MFMA_H(f16x8 a, f16x8 b, f32x4 c) {
  return __builtin_amdgcn_mfma_f32_16x16x32_f16(a, b, c, 0, 0, 0);
}
__device__ __forceinline__ ushort_t f2bf(float x) {
  uint32_t u = __float_as_uint(x);
  u += 0x7fffu + ((u >> 16) & 1u);
  return (ushort_t)(u >> 16);
}
#define GLDS(gsrc, ldst)                                                    \
  __builtin_amdgcn_global_load_lds(                                         \
      (const __attribute__((address_space(1))) uint32_t*)(const void*)(gsrc), \
      (__attribute__((address_space(3))) uint32_t*)(void*)(ldst), 16, 0, 0)

// ---------------------------------------------------------------------------
// K0: tile-transpose f32 [8192][256] -> fp16 [256][8192]. grid (128, 4, 3).
__global__ __launch_bounds__(256) void k_transpose(
    const float* __restrict__ x2, const float* __restrict__ E,
    const float* __restrict__ F, _Float16* __restrict__ xt) {
  __shared__ float tile[64][65];
  const int t = threadIdx.x;
  const int n0 = blockIdx.x * 64;
  const int c0 = blockIdx.y * 64;
  const int z = blockIdx.z;
  const float* __restrict__ src = (z == 0) ? x2 : (z == 1) ? E : F;
  _Float16* __restrict__ dst = xt + (size_t)z * 2097152;
  const int rr = t >> 4, cc = (t & 15) * 4;
#pragma unroll
  for (int i = 0; i < 4; ++i) {
    float4 v = *(const float4*)&src[(size_t)(n0 + rr + 16 * i) * 256 + c0 + cc];
    tile[cc + 0][rr + 16 * i] = v.x;
    tile[cc + 1][rr + 16 * i] = v.y;
    tile[cc + 2][rr + 16 * i] = v.z;
    tile[cc + 3][rr + 16 * i] = v.w;
  }
  __syncthreads();
#pragma unroll
  for (int rnd = 0; rnd < 2; ++rnd) {
    const int u = rnd * 256 + t;
    const int c = u >> 3, r0 = (u & 7) * 8;
    f16x8 h;
#pragma unroll
    for (int j = 0; j < 8; ++j) h[j] = (_Float16)tile[c][r0 + j];
    *(f16x8*)&dst[(size_t)(c0 + c) * 8192 + n0 + r0] = h;
  }
}

// ---------------------------------------------------------------------------
// K1: split-K fp16 MFMA GEMM: part[which][chunk] += A(=Et/Ft)[kp] . B(=x2t)[d]
// grid (4 quadrants, 16 chunks, 2 which), 256 thr, [128x128] tile, K=512.
__global__ __launch_bounds__(256, 2) void k_etx2_mfma(
    const _Float16* __restrict__ xt, float* __restrict__ part) {
  __shared__ __align__(16) _Float16 ab[2][2][8192];  // 64 KB dbuf
  const int t = threadIdx.x;
  const int wv = t >> 6, ln = t & 63;
  const int l15 = ln & 15, g = ln >> 4;
  const int wr = wv >> 1, wc = wv & 1;
  const int kp0 = (blockIdx.x >> 1) * 128;
  const int d0 = (blockIdx.x & 1) * 128;
  const int chunk = blockIdx.y;
  const int which = blockIdx.z;
  const int n0 = chunk * 512;
  const _Float16* __restrict__ A = xt + (size_t)(1 + which) * 2097152;
  const _Float16* __restrict__ B = xt;

  auto stage = [&](int buf, int ks) {
#pragma unroll
    for (int m = 0; m < 2; ++m)
#pragma unroll
      for (int rnd = 0; rnd < 4; ++rnd) {
        const int u = rnd * 256 + t;
        const int row = u >> 3;
        const int cb = (u & 7) << 4;
        const int csw = cb ^ ((row & 7) << 4);
        const _Float16* gs =
            (m ? B + (size_t)(d0 + row) * 8192 : A + (size_t)(kp0 + row) * 8192) +
            n0 + ks * 64 + (csw >> 1);
        GLDS(gs, (char*)&ab[buf][m][0] + (u & ~63) * 16);
      }
  };

  f32x4 acc[4][4];
#pragma unroll
  for (int i = 0; i < 4; ++i)
#pragma unroll
    for (int j = 0; j < 4; ++j) acc[i][j] = {0.f, 0.f, 0.f, 0.f};

  stage(0, 0);
  __syncthreads();
  for (int ks = 0; ks < 8; ++ks) {
    if (ks < 7) stage((ks + 1) & 1, ks + 1);
    const char* la = (const char*)&ab[ks & 1][0][0];
    const char* lb = (const char*)&ab[ks & 1][1][0];
#pragma unroll
    for (int kk = 0; kk < 2; ++kk) {
      f16x8 af[4], bf[4];
#pragma unroll
      for (int i = 0; i < 4; ++i) {
        const int ra = wr * 64 + i * 16 + l15;
        af[i] = *(const f16x8*)(la + ra * 128 +
                                ((kk * 64 + g * 16) ^ ((ra & 7) << 4)));
      }
#pragma unroll
      for (int j = 0; j < 4; ++j) {
        const int rb = wc * 64 + j * 16 + l15;
        bf[j] = *(const f16x8*)(lb + rb * 128 +
                                ((kk * 64 + g * 16) ^ ((rb & 7) << 4)));
      }
#pragma unroll
      for (int i = 0; i < 4; ++i)
#pragma unroll
        for (int j = 0; j < 4; ++j) acc[i][j] = MFMA_H(af[i], bf[j], acc[i][j]);
    }
    __syncthreads();
  }
  float* __restrict__ p = part + ((size_t)which * 16 + chunk) * 65536;
#pragma unroll
  for (int i = 0; i < 4; ++i)
#pragma unroll
    for (int j = 0; j < 4; ++j)
#pragma unroll
      for (int r = 0; r < 4; ++r)
        p[(size_t)(kp0 + wr * 64 + i * 16 + g * 4 + r) * 256 + d0 + wc * 64 +
          j * 16 + l15] = acc[i][j][r];
}

// K1b: reduce 16 partials. gh = [G(65536) | Hh(65536)]. grid 512.
__global__ __launch_bounds__(256) void k_reduce_part(
    const float* __restrict__ part, float* __restrict__ gh) {
  const int oid = blockIdx.x * 256 + threadIdx.x;
  const int which = oid >> 16;
  const int base = oid & 65535;
  const float* __restrict__ p = part + (size_t)which * 16 * 65536 + base;
  float s = 0.f;
#pragma unroll
  for (int c = 0; c < 16; ++c) s += p[c * 65536];
  gh[oid] = s;
}

// K2: klow = G @ Wk, vlow = Hh @ Wv. (unchanged)
__global__ __launch_bounds__(256) void k_lowproj(
    const float* __restrict__ gh, const float* __restrict__ Wk,
    const float* __restrict__ Wv, float* __restrict__ kvlow) {
  __shared__ float a_s[64][17];
  __shared__ float b_s[16][68];
  const int t = threadIdx.x;
  const int which = blockIdx.y;
  const float* __restrict__ A = gh + (size_t)which * 65536;
  const float* __restrict__ W = which ? Wv : Wk;
  float* __restrict__ outp = kvlow + (size_t)which * 65536;
  const int rt = (blockIdx.x >> 2) * 64;
  const int ct = (blockIdx.x & 3) * 64;
  float acc[4][4] = {};
  const int rb = (t >> 4) * 4;
  const int cb = (t & 15) * 4;
  for (int k0 = 0; k0 < 256; k0 += 16) {
    const int ar = t >> 2, ac = (t & 3) * 4;
    float4 av = *(const float4*)&A[(size_t)(rt + ar) * 256 + k0 + ac];
    a_s[ar][ac] = av.x; a_s[ar][ac + 1] = av.y;
    a_s[ar][ac + 2] = av.z; a_s[ar][ac + 3] = av.w;
    const int br = t >> 4, bc = (t & 15) * 4;
    *(float4*)&b_s[br][bc] = *(const float4*)&W[(size_t)(k0 + br) * 256 + ct + bc];
    __syncthreads();
#pragma unroll
    for (int kk = 0; kk < 16; ++kk) {
      float a[4], b[4];
#pragma unroll
      for (int i = 0; i < 4; ++i) a[i] = a_s[rb + i][kk];
#pragma unroll
      for (int j = 0; j < 4; ++j) b[j] = b_s[kk][cb + j];
#pragma unroll
      for (int i = 0; i < 4; ++i)
#pragma unroll
        for (int j = 0; j < 4; ++j) acc[i][j] += a[i] * b[j];
    }
    __syncthreads();
  }
#pragma unroll
  for (int i = 0; i < 4; ++i)
#pragma unroll
    for (int j = 0; j < 4; ++j)
      outp[(size_t)(rt + rb + i) * 256 + ct + cb + j] = acc[i][j];
}

// K3-prep: bf16 conversions/transposes. grid (256, 4), 256 thr. (unchanged)
__global__ __launch_bounds__(256) void k_prep(
    const float* __restrict__ Wq, const float* __restrict__ Wo,
    const float* __restrict__ kvlow, ushort_t* __restrict__ wqt,
    ushort_t* __restrict__ wot, ushort_t* __restrict__ klowb,
    ushort_t* __restrict__ vtb) {
  const int id = blockIdx.x * 256 + threadIdx.x;
  const int task = blockIdx.y;
  if (task == 0) {
    int n = id >> 8, k = id & 255;
    wqt[id] = f2bf(Wq[k * 256 + n] * 0.25503488f);
  } else if (task == 1) {
    int n = id >> 8, k = id & 255;
    wot[id] = f2bf(Wo[k * 256 + n]);
  } else if (task == 2) {
    klowb[id] = f2bf(kvlow[id]);
  } else {
    int kl = id & 127;
    int d = (id >> 7) & 31;
    int kh = (id >> 12) & 1;
    int h = id >> 13;
    int ksw = kl ^ ((d & 7) << 3);
    vtb[(((h * 2 + kh) * 32 + d) << 7) + ksw] =
        f2bf(kvlow[65536 + (kh * 128 + kl) * 256 + h * 32 + d]);
  }
}

// K4: fused MFMA kernel. grid 512, 256 thr. (unchanged from round 2)
__global__ __launch_bounds__(256, 2) void k_fused_mfma(
    const float* __restrict__ x1, const ushort_t* __restrict__ wqt,
    const ushort_t* __restrict__ wot, const ushort_t* __restrict__ klowb,
    const ushort_t* __restrict__ vtb, float* __restrict__ out) {
  __shared__ __align__(16) ushort_t q_lds[16384];
  __shared__ __align__(16) ushort_t wstage[2][4096];
  __shared__ __align__(16) ushort_t o_slice[4][640];
  __shared__ __align__(16) uint32_t p_buf[4][320];
  const int t = threadIdx.x;
  const int wv = t >> 6, ln = t & 63;
  const int l15 = ln & 15, g = ln >> 4;
  const size_t r0 = (size_t)blockIdx.x * 64;
  char* qb = (char*)q_lds;

  auto stage_w = [&](const ushort_t* base, int row0, int wbyte, int buf) {
#pragma unroll
    for (int rnd = 0; rnd < 2; ++rnd) {
      int u = rnd * 256 + wv * 64 + ln;
      const ushort_t* gsrc =
          base + (size_t)(row0 + (u >> 2)) * 256 + (wbyte >> 1) + (u & 3) * 8;
      GLDS(gsrc, &wstage[buf][rnd * 2048 + wv * 512]);
    }
  };
  auto stage_c = [&](const ushort_t* base, int buf) {
#pragma unroll
    for (int rnd = 0; rnd < 2; ++rnd) {
      int u = rnd * 256 + wv * 64 + ln;
      GLDS(base + u * 8, &wstage[buf][rnd * 2048 + wv * 512]);
    }
  };

  // ---- phase 1: Q = x1 @ Wq^T (scaled)
  f32x4 qacc[16];
#pragma unroll
  for (int i = 0; i < 16; ++i) qacc[i] = {0.f, 0.f, 0.f, 0.f};

  stage_w(wqt, 0, 0, 0);
  const float* xrow = x1 + (r0 + wv * 16 + l15) * 256;
  float4 xa = *(const float4*)(xrow + g * 8);
  float4 xb = *(const float4*)(xrow + g * 8 + 4);
  __syncthreads();

  for (int ci = 0; ci < 16; ++ci) {
    const int nh = ci & 1;
    if (ci < 15)
      stage_w(wqt, ((ci + 1) & 1) * 128, ((ci + 1) >> 1) * 64, (ci + 1) & 1);
    else
      stage_w(klowb, 0, 0, 0);
    bf16x8 afrag;
    afrag[0] = (short)f2bf(xa.x); afrag[1] = (short)f2bf(xa.y);
    afrag[2] = (short)f2bf(xa.z); afrag[3] = (short)f2bf(xa.w);
    afrag[4] = (short)f2bf(xb.x); afrag[5] = (short)f2bf(xb.y);
    afrag[6] = (short)f2bf(xb.z); afrag[7] = (short)f2bf(xb.w);
    const ushort_t* cw = wstage[ci & 1];
#pragma unroll
    for (int tt = 0; tt < 8; ++tt) {
      bf16x8 bfr = *(const bf16x8*)&cw[(tt * 16 + l15) * 32 + g * 8];
      qacc[nh * 8 + tt] = MFMA(afrag, bfr, qacc[nh * 8 + tt]);
    }
    if (nh == 1 && ci < 15) {
      int ks = (ci >> 1) + 1;
      xa = *(const float4*)(xrow + ks * 32 + g * 8);
      xb = *(const float4*)(xrow + ks * 32 + g * 8 + 4);
    }
    __syncthreads();
  }
#pragma unroll
  for (int tt = 0; tt < 16; ++tt)
#pragma unroll
    for (int r = 0; r < 4; ++r) {
      int row = wv * 16 + g * 4 + r;
      int lcol = (tt * 16 + l15) * 2;
      *(ushort_t*)(qb + row * 512 + (lcol ^ ((row & 7) << 4))) =
          f2bf(qacc[tt][r]);
    }
  __builtin_amdgcn_sched_barrier(0);

  // ---- phase 2: per head
  f32x4 yacc[16];
#pragma unroll
  for (int i = 0; i < 16; ++i) yacc[i] = {0.f, 0.f, 0.f, 0.f};

  for (int h = 0; h < 8; ++h) {
    stage_w(klowb, 128, h * 64, 1);
    int qrow = wv * 16 + l15;
    bf16x8 qfrag = *(const bf16x8*)(qb + qrow * 512 +
                                    ((h * 64 + g * 16) ^ ((l15 & 7) << 4)));
    f32x4 s[16];
    {
      const ushort_t* ck = wstage[0];
#pragma unroll
      for (int tt = 0; tt < 8; ++tt) {
        bf16x8 afr = *(const bf16x8*)&ck[(tt * 16 + l15) * 32 + g * 8];
        f32x4 z = {0.f, 0.f, 0.f, 0.f};
        s[tt] = MFMA(afr, qfrag, z);
      }
    }
    __syncthreads();
    stage_c(vtb + (h * 2 + 0) * 4096, 0);
    {
      const ushort_t* ck = wstage[1];
#pragma unroll
      for (int tt = 0; tt < 8; ++tt) {
        bf16x8 afr = *(const bf16x8*)&ck[(tt * 16 + l15) * 32 + g * 8];
        f32x4 z = {0.f, 0.f, 0.f, 0.f};
        s[8 + tt] = MFMA(afr, qfrag, z);
      }
    }
    __syncthreads();
    stage_c(vtb + (h * 2 + 1) * 4096, 1);
    float m = -3.0e38f;
#pragma unroll
    for (int tt = 0; tt < 16; ++tt)
#pragma unroll
      for (int r = 0; r < 4; ++r) m = fmaxf(m, s[tt][r]);
    m = fmaxf(m, __shfl_xor(m, 16));
    m = fmaxf(m, __shfl_xor(m, 32));
    float sum = 0.f;
#pragma unroll
    for (int tt = 0; tt < 16; ++tt)
#pragma unroll
      for (int r = 0; r < 4; ++r) {
        float e = exp2f(s[tt][r] - m);
        s[tt][r] = e;
        sum += e;
      }
    sum += __shfl_xor(sum, 16);
    sum += __shfl_xor(sum, 32);
    float rinv = 1.0f / sum;
    uint32_t pw[16][2];
#pragma unroll
    for (int tt = 0; tt < 16; ++tt)
#pragma unroll
      for (int p = 0; p < 2; ++p)
        pw[tt][p] = (uint32_t)f2bf(s[tt][2 * p] * rinv) |
                    ((uint32_t)f2bf(s[tt][2 * p + 1] * rinv) << 16);
    f32x4 oacc[2];
    oacc[0] = {0.f, 0.f, 0.f, 0.f};
    oacc[1] = {0.f, 0.f, 0.f, 0.f};
    uint32_t* pbw = &p_buf[wv][l15 * 20];
    {
      const char* cv = (const char*)wstage[0];
#pragma unroll
      for (int ksl = 0; ksl < 4; ++ksl) {
        pbw[2 * g + 0] = pw[2 * ksl][0];
        pbw[2 * g + 1] = pw[2 * ksl][1];
        pbw[8 + 2 * g + 0] = pw[2 * ksl + 1][0];
        pbw[8 + 2 * g + 1] = pw[2 * ksl + 1][1];
        __builtin_amdgcn_sched_barrier(0);
        bf16x8 pfr = *(const bf16x8*)&p_buf[wv][l15 * 20 + 4 * g];
#pragma unroll
        for (int nt = 0; nt < 2; ++nt) {
          bf16x8 vfr = *(const bf16x8*)(cv + (nt * 16 + l15) * 256 +
                                        ((ksl * 64 + g * 16) ^ ((l15 & 7) << 4)));
          oacc[nt] = MFMA(pfr, vfr, oacc[nt]);
        }
        __builtin_amdgcn_sched_barrier(0);
      }
    }
    __syncthreads();
    stage_w(wot, 0, h * 64, 0);
    {
      const char* cv = (const char*)wstage[1];
#pragma unroll
      for (int ksl = 0; ksl < 4; ++ksl) {
        pbw[2 * g + 0] = pw[8 + 2 * ksl][0];
        pbw[2 * g + 1] = pw[8 + 2 * ksl][1];
        pbw[8 + 2 * g + 0] = pw[9 + 2 * ksl][0];
        pbw[8 + 2 * g + 1] = pw[9 + 2 * ksl][1];
        __builtin_amdgcn_sched_barrier(0);
        bf16x8 pfr = *(const bf16x8*)&p_buf[wv][l15 * 20 + 4 * g];
#pragma unroll
        for (int nt = 0; nt < 2; ++nt) {
          bf16x8 vfr = *(const bf16x8*)(cv + (nt * 16 + l15) * 256 +
                                        ((ksl * 64 + g * 16) ^ ((l15 & 7) << 4)));
          oacc[nt] = MFMA(pfr, vfr, oacc[nt]);
        }
        __builtin_amdgcn_sched_barrier(0);
      }
    }
#pragma unroll
    for (int nt = 0; nt < 2; ++nt)
#pragma unroll
      for (int r = 0; r < 4; ++r)
        o_slice[wv][(g * 4 + r) * 40 + nt * 16 + l15] = f2bf(oacc[nt][r]);
    __builtin_amdgcn_sched_barrier(0);
    __syncthreads();
    stage_w(wot, 128, h * 64, 1);
    bf16x8 ofrag = *(const bf16x8*)&o_slice[wv][l15 * 40 + g * 8];
    {
      const ushort_t* cw = wstage[0];
#pragma unroll
      for (int tt = 0; tt < 8; ++tt) {
        bf16x8 bfr = *(const bf16x8*)&cw[(tt * 16 + l15) * 32 + g * 8];
        yacc[tt] = MFMA(ofrag, bfr, yacc[tt]);
      }
    }
    __syncthreads();
    if (h < 7) stage_w(klowb, 0, (h + 1) * 64, 0);
    {
      const ushort_t* cw = wstage[1];
#pragma unroll
      for (int tt = 0; tt < 8; ++tt) {
        bf16x8 bfr = *(const bf16x8*)&cw[(tt * 16 + l15) * 32 + g * 8];
        yacc[8 + tt] = MFMA(ofrag, bfr, yacc[8 + tt]);
      }
    }
    __syncthreads();
  }

#pragma unroll
  for (int tt = 0; tt < 16; ++tt)
#pragma unroll
    for (int r = 0; r < 4; ++r)
      out[(r0 + wv * 16 + g * 4 + r) * 256 + tt * 16 + l15] = yacc[tt][r];
}

extern "C" void kernel_launch(void* const* d_in, const int* in_sizes, int n_in,
                              void* d_out, int out_size, void* d_ws, size_t ws_size,
                              hipStream_t stream) {
  const float* x1 = (const float*)d_in[0];
  const float* x2 = (const float*)d_in[1];
  const float* Wq = (const float*)d_in[2];
  const float* Wk = (const float*)d_in[3];
  const float* Wv = (const float*)d_in[4];
  const float* Wo = (const float*)d_in[5];
  const float* E  = (const float*)d_in[6];
  const float* F  = (const float*)d_in[7];
  float* out = (float*)d_out;
  float* ws = (float*)d_ws;
  // ws (floats): part [2][16][65536] @0 ; gh @2097152 ; kvlow @2228224 ;
  //   bf16 (wqt|wot|klowb|vtb, ushort 65536 ea) @2359296 ;
  //   xt fp16 [3][256][8192] @2490368  (total 5,636,096 floats = 22.5 MB)
  float* part = ws;
  float* gh = ws + 2097152;
  float* kvlow = ws + 2228224;
  ushort_t* wqt = (ushort_t*)(ws + 2359296);
  ushort_t* wot = wqt + 65536;
  ushort_t* klowb = wot + 65536;
  ushort_t* vtb = klowb + 65536;
  _Float16* xt = (_Float16*)(ws + 2490368);

  k_transpose<<<dim3(128, 4, 3), 256, 0, stream>>>(x2, E, F, xt);
  k_etx2_mfma<<<dim3(4, 16, 2), 256, 0, stream>>>(xt, part);
  k_reduce_part<<<512, 256, 0, stream>>>(part, gh);
  k_lowproj<<<dim3(16, 2), 256, 0, stream>>>(gh, Wk, Wv, kvlow);
  k_prep<<<dim3(256, 4), 256, 0, stream>>>(Wq, Wo, kvlow, wqt, wot, klowb, vtb);
  k_fused_mfma<<<512, 256, 0, stream>>>(x1, wqt, wot, klowb, vtb, out);
}

// Round 4
// 98.814 us; speedup vs baseline: 7.1441x; 1.0691x over previous
//
#include <hip/hip_runtime.h>
#include <math.h>
#include <stdint.h>

// B=4, NQ=8192, NKV=8192, D=256, H=8, HD=32, KP=256. ROWS = 32768.
// Pipeline:
//  k_transpose: x2,E,F f32 [8192][256] -> xt fp16 [3][256][8192]
//  k_prep_w:    Wq->wqt bf16 (xposed, *scale*log2e), Wo->wot bf16, Wk/Wv->fp16
//  k_etx2_mfma: G=E^T x2, Hh=F^T x2 (fp16 MFMA, split-K 32) -> part f32
//  k_reduce:    sum 32 partials -> ghh fp16 [2][256][256]
//  k_lowproj:   klow=G@Wk, vlow=Hh@Wv (fp16 MFMA) -> kvlow f32
//  k_prep2:     klowA bf16 (A-frag XOR layout), vtb bf16 (V^T per head, swz)
//  k_qgemm:     Q = x1@Wq^T -> Qf bf16 in MFMA-B-frag layout
//  k_attn:      per (row-tile, head): St=mfma(klow,Q), exp2 softmax (no max),
//               PV via p_buf repack -> O bf16 [32768][256]
//  k_ogemm:     out = O @ Wo^T (f32)

typedef unsigned short ushort_t;
typedef __attribute__((ext_vector_type(8))) short bf16x8;
typedef __attribute__((ext_vector_type(8))) _Float16 f16x8;
typedef __attribute__((ext_vector_type(4))) float f32x4;

__device__ __forceinline__ f32x4 MFMA(bf16x8 a, bf16x8 b, f32x4 c) {
  return __builtin_amdgcn_mfma_f32_16x16x32_bf16(a, b, c, 0, 0, 0);
}
__device__ __forceinline__ f32x4 MFMA_H(f16x8 a, f16x8 b, f32x4 c) {
  return __builtin_amdgcn_mfma_f32_16x16x32_f16(a, b, c, 0, 0, 0);
}
__device__ __forceinline__ ushort_t f2bf(float x) {
  uint32_t u = __float_as_uint(x);
  u += 0x7fffu + ((u >> 16) & 1u);
  return (ushort_t)(u >> 16);
}
#define GLDS(gsrc, ldst)                                                    \
  __builtin_amdgcn_global_load_lds(                                         \
      (const __attribute__((address_space(1))) uint32_t*)(const void*)(gsrc), \
      (__attribute__((address_space(3))) uint32_t*)(void*)(ldst), 16, 0, 0)

// 3-bit XOR chunk staging: LDS holds [128 rows][64B] window; read addr
// byte = (row*64 + g*16) ^ ((row&7)<<4) is conflict-free (2-way).
// Source mapping (inverse of the XOR bijection): row0=u2^u4, row1=u3,
// row2=u4, row3+=u5+; g0=u0^u2^u4, g1=u1^u3.
#define STAGE_ROW(u) \
  (((((u) >> 2) ^ ((u) >> 4)) & 1) | (((u) >> 2) & 6) | (((u) >> 5) << 3))
#define STAGE_G(u) \
  ((((u) ^ ((u) >> 2) ^ ((u) >> 4)) & 1) | (((((u) >> 1) ^ ((u) >> 3)) & 1) << 1))

// ---------------------------------------------------------------------------
// K0: tile-transpose f32 [8192][256] -> fp16 [256][8192]. grid (128, 4, 3).
__global__ __launch_bounds__(256) void k_transpose(
    const float* __restrict__ x2, const float* __restrict__ E,
    const float* __restrict__ F, _Float16* __restrict__ xt) {
  __shared__ float tile[64][65];
  const int t = threadIdx.x;
  const int n0 = blockIdx.x * 64;
  const int c0 = blockIdx.y * 64;
  const int z = blockIdx.z;
  const float* __restrict__ src = (z == 0) ? x2 : (z == 1) ? E : F;
  _Float16* __restrict__ dst = xt + (size_t)z * 2097152;
  const int rr = t >> 4, cc = (t & 15) * 4;
#pragma unroll
  for (int i = 0; i < 4; ++i) {
    float4 v = *(const float4*)&src[(size_t)(n0 + rr + 16 * i) * 256 + c0 + cc];
    tile[cc + 0][rr + 16 * i] = v.x;
    tile[cc + 1][rr + 16 * i] = v.y;
    tile[cc + 2][rr + 16 * i] = v.z;
    tile[cc + 3][rr + 16 * i] = v.w;
  }
  __syncthreads();
#pragma unroll
  for (int rnd = 0; rnd < 2; ++rnd) {
    const int u = rnd * 256 + t;
    const int c = u >> 3, r0 = (u & 7) * 8;
    f16x8 h;
#pragma unroll
    for (int j = 0; j < 8; ++j) h[j] = (_Float16)tile[c][r0 + j];
    *(f16x8*)&dst[(size_t)(c0 + c) * 8192 + n0 + r0] = h;
  }
}

// ---------------------------------------------------------------------------
// K-prep-w: weight transposes. grid (256, 4).
__global__ __launch_bounds__(256) void k_prep_w(
    const float* __restrict__ Wq, const float* __restrict__ Wk,
    const float* __restrict__ Wv, const float* __restrict__ Wo,
    ushort_t* __restrict__ wqt, ushort_t* __restrict__ wot,
    _Float16* __restrict__ wkt, _Float16* __restrict__ wvt) {
  const int id = blockIdx.x * 256 + threadIdx.x;  // id = n*256 + k
  const int task = blockIdx.y;
  const int n = id >> 8, k = id & 255;
  if (task == 0) wqt[id] = f2bf(Wq[k * 256 + n] * 0.25503488f);  // scale*log2e
  else if (task == 1) wot[id] = f2bf(Wo[k * 256 + n]);
  else if (task == 2) wkt[id] = (_Float16)Wk[k * 256 + n];
  else wvt[id] = (_Float16)Wv[k * 256 + n];
}

// ---------------------------------------------------------------------------
// K1: split-K fp16 MFMA GEMM: part[which][chunk] = Et/Ft[kp-rows] . x2t[d-rows]
// grid (4 quadrants, 32 chunks, 2 which), 256 thr, [128x128] tile, K=256.
__global__ __launch_bounds__(256, 2) void k_etx2_mfma(
    const _Float16* __restrict__ xt, float* __restrict__ part) {
  __shared__ __align__(16) _Float16 ab[2][2][8192];  // 64 KB dbuf
  const int t = threadIdx.x;
  const int ln = t & 63;
  const int wv = t >> 6;
  const int l15 = ln & 15, g = ln >> 4;
  const int wr = wv >> 1, wc = wv & 1;
  const int kp0 = (blockIdx.x >> 1) * 128;
  const int d0 = (blockIdx.x & 1) * 128;
  const int chunk = blockIdx.y;
  const int which = blockIdx.z;
  const int n0 = chunk * 256;
  const _Float16* __restrict__ A = xt + (size_t)(1 + which) * 2097152;
  const _Float16* __restrict__ B = xt;

  auto stage = [&](int buf, int ks) {
#pragma unroll
    for (int m = 0; m < 2; ++m)
#pragma unroll
      for (int rnd = 0; rnd < 4; ++rnd) {
        const int u = rnd * 256 + t;
        const int row = u >> 3;
        const int cb = (u & 7) << 4;
        const int csw = cb ^ ((row & 7) << 4);
        const _Float16* gs =
            (m ? B + (size_t)(d0 + row) * 8192 : A + (size_t)(kp0 + row) * 8192) +
            n0 + ks * 64 + (csw >> 1);
        GLDS(gs, (char*)&ab[buf][m][0] + (u & ~63) * 16);
      }
  };

  f32x4 acc[4][4];
#pragma unroll
  for (int i = 0; i < 4; ++i)
#pragma unroll
    for (int j = 0; j < 4; ++j) acc[i][j] = {0.f, 0.f, 0.f, 0.f};

  stage(0, 0);
  __syncthreads();
  for (int ks = 0; ks < 4; ++ks) {
    if (ks < 3) stage((ks + 1) & 1, ks + 1);
    const char* la = (const char*)&ab[ks & 1][0][0];
    const char* lb = (const char*)&ab[ks & 1][1][0];
#pragma unroll
    for (int kk = 0; kk < 2; ++kk) {
      f16x8 af[4], bf[4];
#pragma unroll
      for (int i = 0; i < 4; ++i) {
        const int ra = wr * 64 + i * 16 + l15;
        af[i] = *(const f16x8*)(la + ra * 128 +
                                ((kk * 64 + g * 16) ^ ((ra & 7) << 4)));
      }
#pragma unroll
      for (int j = 0; j < 4; ++j) {
        const int rb = wc * 64 + j * 16 + l15;
        bf[j] = *(const f16x8*)(lb + rb * 128 +
                                ((kk * 64 + g * 16) ^ ((rb & 7) << 4)));
      }
#pragma unroll
      for (int i = 0; i < 4; ++i)
#pragma unroll
        for (int j = 0; j < 4; ++j) acc[i][j] = MFMA_H(af[i], bf[j], acc[i][j]);
    }
    __syncthreads();
  }
  float* __restrict__ p = part + ((size_t)which * 32 + chunk) * 65536;
#pragma unroll
  for (int i = 0; i < 4; ++i)
#pragma unroll
    for (int j = 0; j < 4; ++j)
#pragma unroll
      for (int r = 0; r < 4; ++r)
        p[(size_t)(kp0 + wr * 64 + i * 16 + g * 4 + r) * 256 + d0 + wc * 64 +
          j * 16 + l15] = acc[i][j][r];
}

// K1b: reduce 32 partials -> ghh fp16 [2][65536]. grid 512.
__global__ __launch_bounds__(256) void k_reduce_part(
    const float* __restrict__ part, _Float16* __restrict__ ghh) {
  const int oid = blockIdx.x * 256 + threadIdx.x;
  const int which = oid >> 16;
  const int base = oid & 65535;
  const float* __restrict__ p = part + (size_t)which * 32 * 65536 + base;
  float s = 0.f;
#pragma unroll
  for (int c = 0; c < 32; ++c) s += p[c * 65536];
  ghh[oid] = (_Float16)s;
}

// ---------------------------------------------------------------------------
// K2: klow = G@Wk, vlow = Hh@Wv via fp16 MFMA. grid (4 rowtiles, 2 which).
__global__ __launch_bounds__(256, 4) void k_lowproj(
    const _Float16* __restrict__ ghh, const _Float16* __restrict__ wkt,
    const _Float16* __restrict__ wvt, float* __restrict__ kvlow) {
  __shared__ __align__(16) _Float16 wstage[2][4096];
  const int t = threadIdx.x;
  const int wv = t >> 6, ln = t & 63;
  const int l15 = ln & 15, g = ln >> 4;
  const int which = blockIdx.y;
  const size_t r0 = (size_t)blockIdx.x * 64;
  const _Float16* __restrict__ A = ghh + (size_t)which * 65536;
  const _Float16* __restrict__ W = which ? wvt : wkt;
  float* __restrict__ outp = kvlow + (size_t)which * 65536;

  auto stage = [&](int row0, int colu, int buf) {
#pragma unroll
    for (int rnd = 0; rnd < 2; ++rnd) {
      const int u = rnd * 256 + wv * 64 + ln;
      const int row = STAGE_ROW(u);
      const int gg = STAGE_G(u);
      GLDS(W + (size_t)(row0 + row) * 256 + colu + gg * 8,
           &wstage[buf][(rnd * 256 + wv * 64) * 8]);
    }
  };

  f32x4 yacc[16];
#pragma unroll
  for (int i = 0; i < 16; ++i) yacc[i] = {0.f, 0.f, 0.f, 0.f};
  stage(0, 0, 0);
  const _Float16* arow = A + (r0 + wv * 16 + l15) * 256;
  __syncthreads();
  for (int ci = 0; ci < 16; ++ci) {
    const int nh = ci & 1, ks = ci >> 1;
    if (ci < 15) stage(((ci + 1) & 1) * 128, ((ci + 1) >> 1) * 32, (ci + 1) & 1);
    f16x8 afrag = *(const f16x8*)(arow + ks * 32 + g * 8);
    const _Float16* cw = wstage[ci & 1];
#pragma unroll
    for (int tt = 0; tt < 8; ++tt) {
      f16x8 bfr = *(const f16x8*)&cw[((tt * 16 + l15) * 32 + g * 8) ^
                                     ((l15 & 7) << 3)];
      yacc[nh * 8 + tt] = MFMA_H(afrag, bfr, yacc[nh * 8 + tt]);
    }
    __syncthreads();
  }
#pragma unroll
  for (int tt = 0; tt < 16; ++tt)
#pragma unroll
    for (int r = 0; r < 4; ++r)
      outp[(r0 + wv * 16 + g * 4 + r) * 256 + tt * 16 + l15] = yacc[tt][r];
}

// ---------------------------------------------------------------------------
// K-prep2: klowA (A-frag XOR layout) + vtb (V^T per head, swizzled). grid (256,2).
__global__ __launch_bounds__(256) void k_prep2(
    const float* __restrict__ kvlow, ushort_t* __restrict__ klowA,
    ushort_t* __restrict__ vtb) {
  const int id = blockIdx.x * 256 + threadIdx.x;  // 0..65535
  if (blockIdx.y == 0) {
    const int h = id >> 13, kp = (id >> 5) & 255, d = id & 31;
    klowA[h * 8192 + (((kp << 5) | d) ^ ((kp & 7) << 3))] =
        f2bf(kvlow[kp * 256 + h * 32 + d]);
  } else {
    const int kl = id & 127, d = (id >> 7) & 31, kh = (id >> 12) & 1, h = id >> 13;
    vtb[(((h * 2 + kh) * 32 + d) << 7) + (kl ^ ((d & 7) << 3))] =
        f2bf(kvlow[65536 + (kh * 128 + kl) * 256 + h * 32 + d]);
  }
}

// ---------------------------------------------------------------------------
// K3: Q-GEMM: Qf (B-frag layout) = x1 @ wqt^T. grid 512, 256 thr.
__global__ __launch_bounds__(256, 4) void k_qgemm(
    const float* __restrict__ x1, const ushort_t* __restrict__ wqt,
    ushort_t* __restrict__ Qf) {
  __shared__ __align__(16) char smem[32768];  // wstage dbuf 16K, then q_re 32K
  const int t = threadIdx.x;
  const int wv = t >> 6, ln = t & 63;
  const int l15 = ln & 15, g = ln >> 4;
  const size_t r0 = (size_t)blockIdx.x * 64;
  ushort_t* wstage = (ushort_t*)smem;

  auto stage = [&](int row0, int colu, int buf) {
#pragma unroll
    for (int rnd = 0; rnd < 2; ++rnd) {
      const int u = rnd * 256 + wv * 64 + ln;
      const int row = STAGE_ROW(u);
      const int gg = STAGE_G(u);
      GLDS(wqt + (size_t)(row0 + row) * 256 + colu + gg * 8,
           &wstage[buf * 4096 + (rnd * 256 + wv * 64) * 8]);
    }
  };

  f32x4 qacc[16];
#pragma unroll
  for (int i = 0; i < 16; ++i) qacc[i] = {0.f, 0.f, 0.f, 0.f};
  stage(0, 0, 0);
  const float* xrow = x1 + (r0 + wv * 16 + l15) * 256;
  float4 xa = *(const float4*)(xrow + g * 8);
  float4 xb = *(const float4*)(xrow + g * 8 + 4);
  __syncthreads();

  for (int ci = 0; ci < 16; ++ci) {
    const int nh = ci & 1;
    if (ci < 15) stage(((ci + 1) & 1) * 128, ((ci + 1) >> 1) * 32, (ci + 1) & 1);
    bf16x8 afrag;
    afrag[0] = (short)f2bf(xa.x); afrag[1] = (short)f2bf(xa.y);
    afrag[2] = (short)f2bf(xa.z); afrag[3] = (short)f2bf(xa.w);
    afrag[4] = (short)f2bf(xb.x); afrag[5] = (short)f2bf(xb.y);
    afrag[6] = (short)f2bf(xb.z); afrag[7] = (short)f2bf(xb.w);
    const ushort_t* cw = &wstage[(ci & 1) * 4096];
#pragma unroll
    for (int tt = 0; tt < 8; ++tt) {
      bf16x8 bfr = *(const bf16x8*)&cw[((tt * 16 + l15) * 32 + g * 8) ^
                                       ((l15 & 7) << 3)];
      qacc[nh * 8 + tt] = MFMA(afrag, bfr, qacc[nh * 8 + tt]);
    }
    if (nh == 1 && ci < 15) {
      int ks = (ci >> 1) + 1;
      xa = *(const float4*)(xrow + ks * 32 + g * 8);
      xb = *(const float4*)(xrow + ks * 32 + g * 8 + 4);
    }
    __syncthreads();
  }
  // epilogue: per-wave LDS repack (C layout -> B-frag layout) + store
  char* myq = smem + wv * 8192;  // overlays wstage; safe after last barrier
#pragma unroll
  for (int tt = 0; tt < 16; ++tt)
#pragma unroll
    for (int r = 0; r < 4; ++r) {
      const int gr = g * 4 + r;
      *(ushort_t*)(myq + gr * 512 + (((tt * 16 + l15) * 2) ^ ((gr & 7) << 4))) =
          f2bf(qacc[tt][r]);
    }
  __builtin_amdgcn_sched_barrier(0);
  const int rt = blockIdx.x * 4 + wv;
#pragma unroll
  for (int hh = 0; hh < 8; ++hh) {
    bf16x8 qf = *(const bf16x8*)(myq + l15 * 512 +
                                 ((hh * 64 + g * 16) ^ ((l15 & 7) << 4)));
    *(bf16x8*)&Qf[((size_t)(rt * 8 + hh) * 64 + ln) * 8] = qf;
  }
}

// ---------------------------------------------------------------------------
// K4: head-parallel attention. grid (256 rowtiles, 8 heads), 512 thr.
__global__ __launch_bounds__(512, 4) void k_attn(
    const ushort_t* __restrict__ Qf, const ushort_t* __restrict__ klowA,
    const ushort_t* __restrict__ vtb, ushort_t* __restrict__ O) {
  __shared__ __align__(16) ushort_t kv[16384];  // klow 8192u | vt 8192u
  __shared__ __align__(16) uint32_t p_buf[8][320];
  __shared__ __align__(16) ushort_t o_sl[8][640];
  const int t = threadIdx.x;
  const int wv = t >> 6, ln = t & 63;
  const int l15 = ln & 15, g = ln >> 4;
  const int h = blockIdx.y;
  const size_t r0 = (size_t)blockIdx.x * 128;

  {  // stage one head's klowA + vtb slices (32 KB), pre-swizzled -> linear
    const ushort_t* ksrc = klowA + h * 8192;
    const ushort_t* vsrc = vtb + h * 8192;
#pragma unroll
    for (int rnd = 0; rnd < 2; ++rnd) {
      const int ub = rnd * 512 + wv * 64;
      GLDS(ksrc + (ub + ln) * 8, &kv[ub * 8]);
    }
#pragma unroll
    for (int rnd = 0; rnd < 2; ++rnd) {
      const int ub = rnd * 512 + wv * 64;
      GLDS(vsrc + (ub + ln) * 8, &kv[8192 + ub * 8]);
    }
  }
  const int rt = blockIdx.x * 8 + wv;
  bf16x8 qfrag = *(const bf16x8*)&Qf[((size_t)(rt * 8 + h) * 64 + ln) * 8];
  __syncthreads();

  // St = mfma(klow, Q): s[tt] = scores for kp = tt*16+g*4+r, q-col = l15
  f32x4 s[16];
#pragma unroll
  for (int tt = 0; tt < 16; ++tt) {
    bf16x8 kfr = *(const bf16x8*)&kv[((tt * 16 + l15) * 32 + g * 8) ^
                                     ((l15 & 7) << 3)];
    f32x4 z = {0.f, 0.f, 0.f, 0.f};
    s[tt] = MFMA(kfr, qfrag, z);
  }
  // exp2-domain softmax, no max-subtract (log2e*scale folded into Wq)
  float sum = 0.f;
  uint32_t pw[16][2];
#pragma unroll
  for (int tt = 0; tt < 16; ++tt) {
    float e0 = exp2f(s[tt][0]), e1 = exp2f(s[tt][1]);
    float e2 = exp2f(s[tt][2]), e3 = exp2f(s[tt][3]);
    sum += (e0 + e1) + (e2 + e3);
    pw[tt][0] = (uint32_t)f2bf(e0) | ((uint32_t)f2bf(e1) << 16);
    pw[tt][1] = (uint32_t)f2bf(e2) | ((uint32_t)f2bf(e3) << 16);
  }
  sum += __shfl_xor(sum, 16);
  sum += __shfl_xor(sum, 32);
  const float rinv = 1.0f / sum;
  float rv[4];
#pragma unroll
  for (int r = 0; r < 4; ++r) rv[r] = __shfl(rinv, g * 4 + r);

  // PV: O[q][d] = sum_kp P*V via per-wave p_buf repack
  f32x4 oacc[2];
  oacc[0] = {0.f, 0.f, 0.f, 0.f};
  oacc[1] = {0.f, 0.f, 0.f, 0.f};
  uint32_t* pbw = &p_buf[wv][l15 * 20];
#pragma unroll
  for (int kh = 0; kh < 2; ++kh) {
    const char* cv = (const char*)&kv[8192 + kh * 4096];
#pragma unroll
    for (int ksl = 0; ksl < 4; ++ksl) {
      const int ks = kh * 4 + ksl;
      pbw[2 * g + 0] = pw[2 * ks][0];
      pbw[2 * g + 1] = pw[2 * ks][1];
      pbw[8 + 2 * g + 0] = pw[2 * ks + 1][0];
      pbw[8 + 2 * g + 1] = pw[2 * ks + 1][1];
      __builtin_amdgcn_sched_barrier(0);
      bf16x8 pfr = *(const bf16x8*)&p_buf[wv][l15 * 20 + 4 * g];
#pragma unroll
      for (int nt = 0; nt < 2; ++nt) {
        bf16x8 vfr = *(const bf16x8*)(cv + (nt * 16 + l15) * 256 +
                                      ((ksl * 64 + g * 16) ^ ((l15 & 7) << 4)));
        oacc[nt] = MFMA(pfr, vfr, oacc[nt]);
      }
      __builtin_amdgcn_sched_barrier(0);
    }
  }
  // O write via per-wave repack (bf16, coalesced 16B stores)
#pragma unroll
  for (int nt = 0; nt < 2; ++nt)
#pragma unroll
    for (int r = 0; r < 4; ++r)
      o_sl[wv][(g * 4 + r) * 40 + nt * 16 + l15] = f2bf(oacc[nt][r] * rv[r]);
  __builtin_amdgcn_sched_barrier(0);
  {
    const int qr = ln >> 2, d0 = (ln & 3) * 8;
    bf16x8 ov = *(const bf16x8*)&o_sl[wv][qr * 40 + d0];
    *(bf16x8*)&O[(r0 + wv * 16 + qr) * 256 + h * 32 + d0] = ov;
  }
}

// ---------------------------------------------------------------------------
// K5: out = O @ wot^T (f32). grid 512, 256 thr.
__global__ __launch_bounds__(256, 4) void k_ogemm(
    const ushort_t* __restrict__ O, const ushort_t* __restrict__ wot,
    float* __restrict__ out) {
  __shared__ __align__(16) ushort_t wstage[2][4096];
  const int t = threadIdx.x;
  const int wv = t >> 6, ln = t & 63;
  const int l15 = ln & 15, g = ln >> 4;
  const size_t r0 = (size_t)blockIdx.x * 64;

  auto stage = [&](int row0, int colu, int buf) {
#pragma unroll
    for (int rnd = 0; rnd < 2; ++rnd) {
      const int u = rnd * 256 + wv * 64 + ln;
      const int row = STAGE_ROW(u);
      const int gg = STAGE_G(u);
      GLDS(wot + (size_t)(row0 + row) * 256 + colu + gg * 8,
           &wstage[buf][(rnd * 256 + wv * 64) * 8]);
    }
  };

  f32x4 yacc[16];
#pragma unroll
  for (int i = 0; i < 16; ++i) yacc[i] = {0.f, 0.f, 0.f, 0.f};
  stage(0, 0, 0);
  const ushort_t* arow = O + (r0 + wv * 16 + l15) * 256;
  __syncthreads();
  for (int ci = 0; ci < 16; ++ci) {
    const int nh = ci & 1, ks = ci >> 1;
    if (ci < 15) stage(((ci + 1) & 1) * 128, ((ci + 1) >> 1) * 32, (ci + 1) & 1);
    bf16x8 afrag = *(const bf16x8*)(arow + ks * 32 + g * 8);
    const ushort_t* cw = wstage[ci & 1];
#pragma unroll
    for (int tt = 0; tt < 8; ++tt) {
      bf16x8 bfr = *(const bf16x8*)&cw[((tt * 16 + l15) * 32 + g * 8) ^
                                       ((l15 & 7) << 3)];
      yacc[nh * 8 + tt] = MFMA(afrag, bfr, yacc[nh * 8 + tt]);
    }
    __syncthreads();
  }
#pragma unroll
  for (int tt = 0; tt < 16; ++tt)
#pragma unroll
    for (int r = 0; r < 4; ++r)
      out[(r0 + wv * 16 + g * 4 + r) * 256 + tt * 16 + l15] = yacc[tt][r];
}

extern "C" void kernel_launch(void* const* d_in, const int* in_sizes, int n_in,
                              void* d_out, int out_size, void* d_ws, size_t ws_size,
                              hipStream_t stream) {
  const float* x1 = (const float*)d_in[0];
  const float* x2 = (const float*)d_in[1];
  const float* Wq = (const float*)d_in[2];
  const float* Wk = (const float*)d_in[3];
  const float* Wv = (const float*)d_in[4];
  const float* Wo = (const float*)d_in[5];
  const float* E  = (const float*)d_in[6];
  const float* F  = (const float*)d_in[7];
  float* out = (float*)d_out;
  float* ws = (float*)d_ws;
  // ws layout (float offsets), total 8,781,824 floats = 35.1 MB:
  //  ghh fp16 @0 (65536) | kvlow f32 @65536 (131072) | wqt @196608 | wot @229376
  //  wkt @262144 | wvt @294912 | klowA @327680 | vtb @360448
  //  part f32 @393216 (4194304)  [overlaid by Qf bf16 after reduce]
  //  xt fp16 @4587520 (3145728)  [overlaid by O bf16 after etx2]
  _Float16* ghh = (_Float16*)ws;
  float* kvlow = ws + 65536;
  ushort_t* wqt = (ushort_t*)(ws + 196608);
  ushort_t* wot = (ushort_t*)(ws + 229376);
  _Float16* wkt = (_Float16*)(ws + 262144);
  _Float16* wvt = (_Float16*)(ws + 294912);
  ushort_t* klowA = (ushort_t*)(ws + 327680);
  ushort_t* vtb = (ushort_t*)(ws + 360448);
  float* part = ws + 393216;
  ushort_t* Qf = (ushort_t*)(ws + 393216);
  _Float16* xt = (_Float16*)(ws + 4587520);
  ushort_t* O = (ushort_t*)(ws + 4587520);

  k_transpose<<<dim3(128, 4, 3), 256, 0, stream>>>(x2, E, F, xt);
  k_prep_w<<<dim3(256, 4), 256, 0, stream>>>(Wq, Wk, Wv, Wo, wqt, wot, wkt, wvt);
  k_etx2_mfma<<<dim3(4, 32, 2), 256, 0, stream>>>(xt, part);
  k_reduce_part<<<512, 256, 0, stream>>>(part, ghh);
  k_lowproj<<<dim3(4, 2), 256, 0, stream>>>(ghh, wkt, wvt, kvlow);
  k_prep2<<<dim3(256, 2), 256, 0, stream>>>(kvlow, klowA, vtb);
  k_qgemm<<<512, 256, 0, stream>>>(x1, wqt, Qf);
  k_attn<<<dim3(256, 8), 512, 0, stream>>>(Qf, klowA, vtb, O);
  k_ogemm<<<512, 256, 0, stream>>>(O, wot, out);
}

// Round 5
// 90.027 us; speedup vs baseline: 7.8413x; 1.0976x over previous
//
#include <hip/hip_runtime.h>
#include <math.h>
#include <stdint.h>

// B=4, NQ=8192, NKV=8192, D=256, H=8, HD=32, KP=256. ROWS = 32768.
// L1 k_prep_all: x2,E,F -> xt fp16 [3][256][8192] (transposed); W transposes
// L2 k_mega1:    qgemm (512 blks): Qf = x1@Wq^T (B-frag layout)
//                + etx2 (128 blks): part = E^T x2 / F^T x2 (fp16 MFMA splitK16)
// L3 k_reduce:   sum 16 partials -> ghh fp16
// L4 k_lowproj2: klow=G@Wk, vlow=Hh@Wv (fp16 MFMA) -> klowA/vtb direct
// L5 k_attn:     per (256-row tile, head): St=mfma(klow,Q), exp2 softmax,
//                PV -> O bf16 (2 row-subtiles per staged KV)
// L6 k_ogemm:    out = O @ Wo^T (f32)

typedef unsigned short ushort_t;
typedef __attribute__((ext_vector_type(8))) short bf16x8;
typedef __attribute__((ext_vector_type(8))) _Float16 f16x8;
typedef __attribute__((ext_vector_type(4))) float f32x4;

__device__ __forceinline__ f32x4 MFMA(bf16x8 a, bf16x8 b, f32x4 c) {
  return __builtin_amdgcn_mfma_f32_16x16x32_bf16(a, b, c, 0, 0, 0);
}
__device__ __forceinline__ f32x4 MFMA_H(f16x8 a, f16x8 b, f32x4 c) {
  return __builtin_amdgcn_mfma_f32_16x16x32_f16(a, b, c, 0, 0, 0);
}
__device__ __forceinline__ ushort_t f2bf(float x) {
  uint32_t u = __float_as_uint(x);
  u += 0x7fffu + ((u >> 16) & 1u);
  return (ushort_t)(u >> 16);
}
#define GLDS(gsrc, ldst)                                                    \
  __builtin_amdgcn_global_load_lds(                                         \
      (const __attribute__((address_space(1))) uint32_t*)(const void*)(gsrc), \
      (__attribute__((address_space(3))) uint32_t*)(void*)(ldst), 16, 0, 0)

// 3-bit XOR chunk staging helpers (proven in rounds 3-4)
#define STAGE_ROW(u) \
  (((((u) >> 2) ^ ((u) >> 4)) & 1) | (((u) >> 2) & 6) | (((u) >> 5) << 3))
#define STAGE_G(u) \
  ((((u) ^ ((u) >> 2) ^ ((u) >> 4)) & 1) | (((((u) >> 1) ^ ((u) >> 3)) & 1) << 1))

// ---------------------------------------------------------------------------
// L1: transposes. grid (128,4,4), 256 thr.
//  z<3: f32 [8192][256] -> fp16 [256][8192] (z: x2,E,F)
//  z==3 (x<16): weight 64x64 tile transpose; y: Wq(bf16*sc) Wo(bf16) Wk Wv(fp16)
__global__ __launch_bounds__(256) void k_prep_all(
    const float* __restrict__ x2, const float* __restrict__ E,
    const float* __restrict__ F, const float* __restrict__ Wq,
    const float* __restrict__ Wk, const float* __restrict__ Wv,
    const float* __restrict__ Wo, _Float16* __restrict__ xt,
    ushort_t* __restrict__ wqt, ushort_t* __restrict__ wot,
    _Float16* __restrict__ wkt, _Float16* __restrict__ wvt) {
  __shared__ float tile[64][65];
  const int t = threadIdx.x;
  const int z = blockIdx.z;
  if (z < 3) {
    const int n0 = blockIdx.x * 64;
    const int c0 = blockIdx.y * 64;
    const float* __restrict__ src = (z == 0) ? x2 : (z == 1) ? E : F;
    _Float16* __restrict__ dst = xt + (size_t)z * 2097152;
    const int rr = t >> 4, cc = (t & 15) * 4;
#pragma unroll
    for (int i = 0; i < 4; ++i) {
      float4 v = *(const float4*)&src[(size_t)(n0 + rr + 16 * i) * 256 + c0 + cc];
      tile[cc + 0][rr + 16 * i] = v.x;
      tile[cc + 1][rr + 16 * i] = v.y;
      tile[cc + 2][rr + 16 * i] = v.z;
      tile[cc + 3][rr + 16 * i] = v.w;
    }
    __syncthreads();
#pragma unroll
    for (int rnd = 0; rnd < 2; ++rnd) {
      const int u = rnd * 256 + t;
      const int c = u >> 3, r0 = (u & 7) * 8;
      f16x8 h;
#pragma unroll
      for (int j = 0; j < 8; ++j) h[j] = (_Float16)tile[c][r0 + j];
      *(f16x8*)&dst[(size_t)(c0 + c) * 8192 + n0 + r0] = h;
    }
  } else {
    if (blockIdx.x >= 16) return;
    const int m = blockIdx.y;
    const float* __restrict__ src = (m == 0) ? Wq : (m == 1) ? Wo
                                  : (m == 2) ? Wk : Wv;
    const int tr = (blockIdx.x >> 2) * 64;  // k range
    const int tc = (blockIdx.x & 3) * 64;   // n range
    const int rr = t >> 4, cc = (t & 15) * 4;
#pragma unroll
    for (int i = 0; i < 4; ++i) {
      float4 v = *(const float4*)&src[(size_t)(tr + rr + 16 * i) * 256 + tc + cc];
      tile[cc + 0][rr + 16 * i] = v.x;
      tile[cc + 1][rr + 16 * i] = v.y;
      tile[cc + 2][rr + 16 * i] = v.z;
      tile[cc + 3][rr + 16 * i] = v.w;
    }
    __syncthreads();
#pragma unroll
    for (int rnd = 0; rnd < 2; ++rnd) {
      const int u = rnd * 256 + t;
      const int nl = u >> 3, kl = (u & 7) * 8;
      if (m < 2) {
        const float sc = (m == 0) ? 0.25503488f : 1.0f;  // scale*log2e
        bf16x8 hv;
#pragma unroll
        for (int j = 0; j < 8; ++j) hv[j] = (short)f2bf(tile[nl][kl + j] * sc);
        ushort_t* dst = (m == 0) ? wqt : wot;
        *(bf16x8*)&dst[(size_t)(tc + nl) * 256 + tr + kl] = hv;
      } else {
        f16x8 hv;
#pragma unroll
        for (int j = 0; j < 8; ++j) hv[j] = (_Float16)tile[nl][kl + j];
        _Float16* dst = (m == 2) ? wkt : wvt;
        *(f16x8*)&dst[(size_t)(tc + nl) * 256 + tr + kl] = hv;
      }
    }
  }
}

// ---------------------------------------------------------------------------
// L2: merged qgemm (bid<512) + etx2 (bid>=512). grid 640, 256 thr.
__global__ __launch_bounds__(256, 3) void k_mega1(
    const float* __restrict__ x1, const _Float16* __restrict__ xt,
    const ushort_t* __restrict__ wqt, ushort_t* __restrict__ Qf,
    float* __restrict__ part) {
  __shared__ __align__(16) char smem[32768];
  const int t = threadIdx.x;
  const int wv = t >> 6, ln = t & 63;
  const int l15 = ln & 15, g = ln >> 4;

  if (blockIdx.x < 512) {
    // ---------------- qgemm: Qf = x1 @ wqt^T (B-frag layout) ----------------
    ushort_t* wstage = (ushort_t*)smem;
    const size_t r0 = (size_t)blockIdx.x * 64;
    auto stage = [&](int row0, int colu, int buf) {
#pragma unroll
      for (int rnd = 0; rnd < 2; ++rnd) {
        const int u = rnd * 256 + wv * 64 + ln;
        const int row = STAGE_ROW(u);
        const int gg = STAGE_G(u);
        GLDS(wqt + (size_t)(row0 + row) * 256 + colu + gg * 8,
             &wstage[(buf * 512 + rnd * 256 + wv * 64) * 8]);
      }
    };
    f32x4 qacc[16];
#pragma unroll
    for (int i = 0; i < 16; ++i) qacc[i] = {0.f, 0.f, 0.f, 0.f};
    stage(0, 0, 0);
    const float* xrow = x1 + (r0 + wv * 16 + l15) * 256;
    float4 xa = *(const float4*)(xrow + g * 8);
    float4 xb = *(const float4*)(xrow + g * 8 + 4);
    __syncthreads();
    for (int ci = 0; ci < 16; ++ci) {
      const int nh = ci & 1;
      if (ci < 15) stage(((ci + 1) & 1) * 128, ((ci + 1) >> 1) * 32, (ci + 1) & 1);
      bf16x8 afrag;
      afrag[0] = (short)f2bf(xa.x); afrag[1] = (short)f2bf(xa.y);
      afrag[2] = (short)f2bf(xa.z); afrag[3] = (short)f2bf(xa.w);
      afrag[4] = (short)f2bf(xb.x); afrag[5] = (short)f2bf(xb.y);
      afrag[6] = (short)f2bf(xb.z); afrag[7] = (short)f2bf(xb.w);
      const ushort_t* cw = &wstage[(ci & 1) * 4096];
#pragma unroll
      for (int tt = 0; tt < 8; ++tt) {
        bf16x8 bfr = *(const bf16x8*)&cw[((tt * 16 + l15) * 32 + g * 8) ^
                                         ((l15 & 7) << 3)];
        qacc[nh * 8 + tt] = MFMA(afrag, bfr, qacc[nh * 8 + tt]);
      }
      if (nh == 1 && ci < 15) {
        int ks = (ci >> 1) + 1;
        xa = *(const float4*)(xrow + ks * 32 + g * 8);
        xb = *(const float4*)(xrow + ks * 32 + g * 8 + 4);
      }
      __syncthreads();
    }
    char* myq = smem + wv * 8192;
#pragma unroll
    for (int tt = 0; tt < 16; ++tt)
#pragma unroll
      for (int r = 0; r < 4; ++r) {
        const int gr = g * 4 + r;
        *(ushort_t*)(myq + gr * 512 + (((tt * 16 + l15) * 2) ^ ((gr & 7) << 4))) =
            f2bf(qacc[tt][r]);
      }
    __builtin_amdgcn_sched_barrier(0);
    const int rt = blockIdx.x * 4 + wv;
#pragma unroll
    for (int hh = 0; hh < 8; ++hh) {
      bf16x8 qf = *(const bf16x8*)(myq + l15 * 512 +
                                   ((hh * 64 + g * 16) ^ ((l15 & 7) << 4)));
      *(bf16x8*)&Qf[((size_t)(rt * 8 + hh) * 64 + ln) * 8] = qf;
    }
  } else {
    // ---------------- etx2: part = E^T x2 / F^T x2 (splitK 16) --------------
    const int bid = blockIdx.x - 512;  // 0..127
    const int which = bid & 1;
    const int chunk = (bid >> 1) & 15;
    const int quad = bid >> 5;  // 0..3
    const int kp0 = (quad >> 1) * 128;
    const int d0 = (quad & 1) * 128;
    const int n0 = chunk * 512;
    const _Float16* __restrict__ A = xt + (size_t)(1 + which) * 2097152;
    const _Float16* __restrict__ B = xt;
    const int wr = wv >> 1, wc = wv & 1;
    f32x4 acc[4][4];
#pragma unroll
    for (int i = 0; i < 4; ++i)
#pragma unroll
      for (int j = 0; j < 4; ++j) acc[i][j] = {0.f, 0.f, 0.f, 0.f};

    for (int ks = 0; ks < 8; ++ks) {
#pragma unroll
      for (int r8 = 0; r8 < 8; ++r8) {
        const int u = r8 * 256 + t;      // 0..2047 16B units
        const int mm = u >> 10;          // 0:A 1:B
        const int uu = u & 1023;
        const int row = uu >> 3;
        const int nsw = ((uu ^ row) & 7) << 3;  // source-swizzled n-elems
        const _Float16* gs =
            (mm ? B + (size_t)(d0 + row) * 8192
                : A + (size_t)(kp0 + row) * 8192) +
            n0 + ks * 64 + nsw;
        GLDS(gs, smem + (u & ~63) * 16);
      }
      __syncthreads();
      const char* la = smem;
      const char* lb = smem + 16384;
#pragma unroll
      for (int kk = 0; kk < 2; ++kk) {
        f16x8 af[4], bf[4];
#pragma unroll
        for (int i = 0; i < 4; ++i) {
          const int ra = wr * 64 + i * 16 + l15;
          af[i] = *(const f16x8*)(la + ra * 128 +
                                  ((kk * 64 + g * 16) ^ ((ra & 7) << 4)));
        }
#pragma unroll
        for (int j = 0; j < 4; ++j) {
          const int rb = wc * 64 + j * 16 + l15;
          bf[j] = *(const f16x8*)(lb + rb * 128 +
                                  ((kk * 64 + g * 16) ^ ((rb & 7) << 4)));
        }
#pragma unroll
        for (int i = 0; i < 4; ++i)
#pragma unroll
          for (int j = 0; j < 4; ++j)
            acc[i][j] = MFMA_H(af[i], bf[j], acc[i][j]);
      }
      __syncthreads();
    }
    float* __restrict__ p = part + ((size_t)which * 16 + chunk) * 65536;
#pragma unroll
    for (int i = 0; i < 4; ++i)
#pragma unroll
      for (int j = 0; j < 4; ++j)
#pragma unroll
        for (int r = 0; r < 4; ++r)
          p[(size_t)(kp0 + wr * 64 + i * 16 + g * 4 + r) * 256 + d0 + wc * 64 +
            j * 16 + l15] = acc[i][j][r];
  }
}

// ---------------------------------------------------------------------------
// L3: reduce 16 partials -> ghh fp16 [2][65536]. grid 512.
__global__ __launch_bounds__(256) void k_reduce_part(
    const float* __restrict__ part, _Float16* __restrict__ ghh) {
  const int oid = blockIdx.x * 256 + threadIdx.x;
  const int which = oid >> 16;
  const int base = oid & 65535;
  const float* __restrict__ p = part + (size_t)which * 16 * 65536 + base;
  float s = 0.f;
#pragma unroll
  for (int c = 0; c < 16; ++c) s += p[c * 65536];
  ghh[oid] = (_Float16)s;
}

// ---------------------------------------------------------------------------
// L4: klow=G@Wk, vlow=Hh@Wv (fp16 MFMA); epilogue writes klowA/vtb directly.
// grid (4 rowtiles, 2 which), 256 thr.
__global__ __launch_bounds__(256, 4) void k_lowproj2(
    const _Float16* __restrict__ ghh, const _Float16* __restrict__ wkt,
    const _Float16* __restrict__ wvt, ushort_t* __restrict__ klowA,
    ushort_t* __restrict__ vtb) {
  __shared__ __align__(16) _Float16 wstage[2][4096];
  const int t = threadIdx.x;
  const int wv = t >> 6, ln = t & 63;
  const int l15 = ln & 15, g = ln >> 4;
  const int which = blockIdx.y;
  const int r0 = blockIdx.x * 64;
  const _Float16* __restrict__ A = ghh + (size_t)which * 65536;
  const _Float16* __restrict__ W = which ? wvt : wkt;

  auto stage = [&](int row0, int colu, int buf) {
#pragma unroll
    for (int rnd = 0; rnd < 2; ++rnd) {
      const int u = rnd * 256 + wv * 64 + ln;
      const int row = STAGE_ROW(u);
      const int gg = STAGE_G(u);
      GLDS(W + (size_t)(row0 + row) * 256 + colu + gg * 8,
           &wstage[buf][(rnd * 256 + wv * 64) * 8]);
    }
  };

  f32x4 yacc[16];
#pragma unroll
  for (int i = 0; i < 16; ++i) yacc[i] = {0.f, 0.f, 0.f, 0.f};
  stage(0, 0, 0);
  const _Float16* arow = A + (size_t)(r0 + wv * 16 + l15) * 256;
  __syncthreads();
  for (int ci = 0; ci < 16; ++ci) {
    const int nh = ci & 1, ks = ci >> 1;
    if (ci < 15) stage(((ci + 1) & 1) * 128, ((ci + 1) >> 1) * 32, (ci + 1) & 1);
    f16x8 afrag = *(const f16x8*)(arow + ks * 32 + g * 8);
    const _Float16* cw = wstage[ci & 1];
#pragma unroll
    for (int tt = 0; tt < 8; ++tt) {
      f16x8 bfr = *(const f16x8*)&cw[((tt * 16 + l15) * 32 + g * 8) ^
                                     ((l15 & 7) << 3)];
      yacc[nh * 8 + tt] = MFMA_H(afrag, bfr, yacc[nh * 8 + tt]);
    }
    __syncthreads();
  }
#pragma unroll
  for (int tt = 0; tt < 16; ++tt)
#pragma unroll
    for (int r = 0; r < 4; ++r) {
      const int rowi = r0 + wv * 16 + g * 4 + r;  // kp (which=0) or n (which=1)
      const int c = tt * 16 + l15;
      const int hh = c >> 5, d = c & 31;
      const ushort_t val = f2bf(yacc[tt][r]);
      if (which == 0) {
        klowA[(hh << 13) + ((((rowi & 255) << 5) | d) ^ ((rowi & 7) << 3))] = val;
      } else {
        const int kh = (rowi >> 7) & 1, kl = rowi & 127;
        vtb[(((hh * 2 + kh) * 32 + d) << 7) + (kl ^ ((d & 7) << 3))] = val;
      }
    }
}

// ---------------------------------------------------------------------------
// L5: attention. grid (128 tiles of 256 rows, 8 heads), 512 thr.
// Each wave: 2 row-subtiles against one staged KV head slice.
__global__ __launch_bounds__(512, 4) void k_attn(
    const ushort_t* __restrict__ Qf, const ushort_t* __restrict__ klowA,
    const ushort_t* __restrict__ vtb, ushort_t* __restrict__ O) {
  __shared__ __align__(16) ushort_t kv[16384];  // klow 8192u | vt 8192u
  __shared__ __align__(16) uint32_t p_buf[8][320];
  __shared__ __align__(16) ushort_t o_sl[8][640];
  const int t = threadIdx.x;
  const int wv = t >> 6, ln = t & 63;
  const int l15 = ln & 15, g = ln >> 4;
  const int h = blockIdx.y;
  const size_t r0 = (size_t)blockIdx.x * 256;

  {  // stage one head's klowA + vtb (32 KB), pre-swizzled -> linear
    const ushort_t* ksrc = klowA + h * 8192;
    const ushort_t* vsrc = vtb + h * 8192;
#pragma unroll
    for (int rnd = 0; rnd < 2; ++rnd) {
      const int ub = rnd * 512 + wv * 64;
      GLDS(ksrc + (ub + ln) * 8, &kv[ub * 8]);
    }
#pragma unroll
    for (int rnd = 0; rnd < 2; ++rnd) {
      const int ub = rnd * 512 + wv * 64;
      GLDS(vsrc + (ub + ln) * 8, &kv[8192 + ub * 8]);
    }
  }
  const int rtb = blockIdx.x * 16 + wv;
  bf16x8 qfA = *(const bf16x8*)&Qf[((size_t)(rtb * 8 + h) * 64 + ln) * 8];
  bf16x8 qfB = *(const bf16x8*)&Qf[((size_t)((rtb + 8) * 8 + h) * 64 + ln) * 8];
  __syncthreads();

#pragma unroll
  for (int st = 0; st < 2; ++st) {
    const bf16x8 qfrag = st ? qfB : qfA;
    // scores: St = mfma(klow, Q)
    f32x4 s[16];
#pragma unroll
    for (int tt = 0; tt < 16; ++tt) {
      bf16x8 kfr = *(const bf16x8*)&kv[((tt * 16 + l15) * 32 + g * 8) ^
                                       ((l15 & 7) << 3)];
      f32x4 z = {0.f, 0.f, 0.f, 0.f};
      s[tt] = MFMA(kfr, qfrag, z);
    }
    // exp2-domain softmax (no max-subtract; log2e*scale folded into Wq)
    float sum = 0.f;
    uint32_t pw[16][2];
#pragma unroll
    for (int tt = 0; tt < 16; ++tt) {
      float e0 = exp2f(s[tt][0]), e1 = exp2f(s[tt][1]);
      float e2 = exp2f(s[tt][2]), e3 = exp2f(s[tt][3]);
      sum += (e0 + e1) + (e2 + e3);
      pw[tt][0] = (uint32_t)f2bf(e0) | ((uint32_t)f2bf(e1) << 16);
      pw[tt][1] = (uint32_t)f2bf(e2) | ((uint32_t)f2bf(e3) << 16);
    }
    sum += __shfl_xor(sum, 16);
    sum += __shfl_xor(sum, 32);
    const float rinv = 1.0f / sum;
    float rv[4];
#pragma unroll
    for (int r = 0; r < 4; ++r) rv[r] = __shfl(rinv, g * 4 + r);

    // PV via per-wave p_buf repack
    f32x4 oacc[2];
    oacc[0] = {0.f, 0.f, 0.f, 0.f};
    oacc[1] = {0.f, 0.f, 0.f, 0.f};
    uint32_t* pbw = &p_buf[wv][l15 * 20];
#pragma unroll
    for (int kh = 0; kh < 2; ++kh) {
      const char* cv = (const char*)&kv[8192 + kh * 4096];
#pragma unroll
      for (int ksl = 0; ksl < 4; ++ksl) {
        const int ks = kh * 4 + ksl;
        pbw[2 * g + 0] = pw[2 * ks][0];
        pbw[2 * g + 1] = pw[2 * ks][1];
        pbw[8 + 2 * g + 0] = pw[2 * ks + 1][0];
        pbw[8 + 2 * g + 1] = pw[2 * ks + 1][1];
        __builtin_amdgcn_sched_barrier(0);
        bf16x8 pfr = *(const bf16x8*)&p_buf[wv][l15 * 20 + 4 * g];
#pragma unroll
        for (int nt = 0; nt < 2; ++nt) {
          bf16x8 vfr = *(const bf16x8*)(cv + (nt * 16 + l15) * 256 +
                                        ((ksl * 64 + g * 16) ^ ((l15 & 7) << 4)));
          oacc[nt] = MFMA(pfr, vfr, oacc[nt]);
        }
        __builtin_amdgcn_sched_barrier(0);
      }
    }
    // O write via per-wave repack
#pragma unroll
    for (int nt = 0; nt < 2; ++nt)
#pragma unroll
      for (int r = 0; r < 4; ++r)
        o_sl[wv][(g * 4 + r) * 40 + nt * 16 + l15] = f2bf(oacc[nt][r] * rv[r]);
    __builtin_amdgcn_sched_barrier(0);
    {
      const int qr = ln >> 2, d0 = (ln & 3) * 8;
      bf16x8 ov = *(const bf16x8*)&o_sl[wv][qr * 40 + d0];
      *(bf16x8*)&O[(r0 + st * 128 + wv * 16 + qr) * 256 + h * 32 + d0] = ov;
    }
    __builtin_amdgcn_sched_barrier(0);
  }
}

// ---------------------------------------------------------------------------
// L6: out = O @ wot^T (f32). grid 512, 256 thr.
__global__ __launch_bounds__(256, 4) void k_ogemm(
    const ushort_t* __restrict__ O, const ushort_t* __restrict__ wot,
    float* __restrict__ out) {
  __shared__ __align__(16) ushort_t wstage[2][4096];
  const int t = threadIdx.x;
  const int wv = t >> 6, ln = t & 63;
  const int l15 = ln & 15, g = ln >> 4;
  const size_t r0 = (size_t)blockIdx.x * 64;

  auto stage = [&](int row0, int colu, int buf) {
#pragma unroll
    for (int rnd = 0; rnd < 2; ++rnd) {
      const int u = rnd * 256 + wv * 64 + ln;
      const int row = STAGE_ROW(u);
      const int gg = STAGE_G(u);
      GLDS(wot + (size_t)(row0 + row) * 256 + colu + gg * 8,
           &wstage[buf][(rnd * 256 + wv * 64) * 8]);
    }
  };

  f32x4 yacc[16];
#pragma unroll
  for (int i = 0; i < 16; ++i) yacc[i] = {0.f, 0.f, 0.f, 0.f};
  stage(0, 0, 0);
  const ushort_t* arow = O + (r0 + wv * 16 + l15) * 256;
  __syncthreads();
  for (int ci = 0; ci < 16; ++ci) {
    const int nh = ci & 1, ks = ci >> 1;
    if (ci < 15) stage(((ci + 1) & 1) * 128, ((ci + 1) >> 1) * 32, (ci + 1) & 1);
    bf16x8 afrag = *(const bf16x8*)(arow + ks * 32 + g * 8);
    const ushort_t* cw = wstage[ci & 1];
#pragma unroll
    for (int tt = 0; tt < 8; ++tt) {
      bf16x8 bfr = *(const bf16x8*)&cw[((tt * 16 + l15) * 32 + g * 8) ^
                                       ((l15 & 7) << 3)];
      yacc[nh * 8 + tt] = MFMA(afrag, bfr, yacc[nh * 8 + tt]);
    }
    __syncthreads();
  }
#pragma unroll
  for (int tt = 0; tt < 16; ++tt)
#pragma unroll
    for (int r = 0; r < 4; ++r)
      out[(r0 + wv * 16 + g * 4 + r) * 256 + tt * 16 + l15] = yacc[tt][r];
}

extern "C" void kernel_launch(void* const* d_in, const int* in_sizes, int n_in,
                              void* d_out, int out_size, void* d_ws, size_t ws_size,
                              hipStream_t stream) {
  const float* x1 = (const float*)d_in[0];
  const float* x2 = (const float*)d_in[1];
  const float* Wq = (const float*)d_in[2];
  const float* Wk = (const float*)d_in[3];
  const float* Wv = (const float*)d_in[4];
  const float* Wo = (const float*)d_in[5];
  const float* E  = (const float*)d_in[6];
  const float* F  = (const float*)d_in[7];
  float* out = (float*)d_out;
  float* ws = (float*)d_ws;
  // ws layout (float offsets), total ~43 MB:
  //  ghh fp16 @0 (65536) | wqt @65536 | wot @98304 | wkt @131072 | wvt @163840
  //  klowA @196608 | vtb @229376 | part f32 @262144 (2,097,152)
  //  Qf bf16 @2359296 (4,194,304) | xt fp16 @6553600 (3,145,728)
  //  O bf16 @6553600 overlays xt (xt dead after L2) .. 10747904
  _Float16* ghh = (_Float16*)ws;
  ushort_t* wqt = (ushort_t*)(ws + 65536);
  ushort_t* wot = (ushort_t*)(ws + 98304);
  _Float16* wkt = (_Float16*)(ws + 131072);
  _Float16* wvt = (_Float16*)(ws + 163840);
  ushort_t* klowA = (ushort_t*)(ws + 196608);
  ushort_t* vtb = (ushort_t*)(ws + 229376);
  float* part = ws + 262144;
  ushort_t* Qf = (ushort_t*)(ws + 2359296);
  _Float16* xt = (_Float16*)(ws + 6553600);
  ushort_t* O = (ushort_t*)(ws + 6553600);

  k_prep_all<<<dim3(128, 4, 4), 256, 0, stream>>>(x2, E, F, Wq, Wk, Wv, Wo, xt,
                                                  wqt, wot, wkt, wvt);
  k_mega1<<<640, 256, 0, stream>>>(x1, xt, wqt, Qf, part);
  k_reduce_part<<<512, 256, 0, stream>>>(part, ghh);
  k_lowproj2<<<dim3(4, 2), 256, 0, stream>>>(ghh, wkt, wvt, klowA, vtb);
  k_attn<<<dim3(128, 8), 512, 0, stream>>>(Qf, klowA, vtb, O);
  k_ogemm<<<512, 256, 0, stream>>>(O, wot, out);
}